// Round 12
// baseline (813.506 us; speedup 1.0000x reference)
//
#include <hip/hip_runtime.h>
#include <math.h>

#define BATCH 8
#define SEQ 512
#define NVAR 1024
#define DM 512
#define NH 8
#define DH 64
#define NE 8
#define NF 8
#define NL 2
#define NTOK (BATCH*NVAR)   // 8192
#define LN_EPS 1e-5f
#define LSC 2048.0f
#define ILSC (1.0f/2048.0f)

typedef __attribute__((ext_vector_type(8))) _Float16 f16x8;
typedef __attribute__((ext_vector_type(2))) _Float16 f16x2;
typedef __attribute__((ext_vector_type(4))) float f32x4;
#define MFMA16 __builtin_amdgcn_mfma_f32_16x16x32_f16

__device__ __forceinline__ void fsplit(float v, _Float16& hi, _Float16& lo) {
    hi = (_Float16)v;
    lo = (_Float16)((v - (float)hi) * LSC);
}
__device__ __forceinline__ float frec(_Float16 hi, _Float16 lo) {
    return (float)hi + (float)lo * ILSC;
}
// packed split: 2 floats -> hi pair + lo pair (1 cvt instr each). RTZ on hi is
// compensated exactly by lo; reconstruction accuracy unchanged (~2^-22 rel).
// NOTE: cvt_pkrtz returns __fp16x2; bit_cast to _Float16x2 (identical layout).
__device__ __forceinline__ void fsplit2(float a, float b, f16x2& h2, f16x2& l2) {
    h2 = __builtin_bit_cast(f16x2, __builtin_amdgcn_cvt_pkrtz(a, b));
    l2 = __builtin_bit_cast(f16x2, __builtin_amdgcn_cvt_pkrtz(
             (a - (float)h2.x)*LSC, (b - (float)h2.y)*LSC));
}

// direct HBM->LDS, 16B/lane; LDS dest = wave-uniform base + lane*16 (linear)
__device__ __forceinline__ void gload_lds16(const _Float16* g, _Float16* l) {
    __builtin_amdgcn_global_load_lds(
        (const __attribute__((address_space(1))) void*)g,
        (__attribute__((address_space(3))) void*)l, 16, 0, 0);
}

// DPP row-of-16 rotation reduce (VALU-only, off the DS pipe)
#define DPPROR(v, C) __int_as_float(__builtin_amdgcn_update_dpp(0, __float_as_int(v), (C), 0xF, 0xF, true))
__device__ __forceinline__ float rowmax16(float v) {
    v = fmaxf(v, DPPROR(v, 0x121));   // row_ror:1
    v = fmaxf(v, DPPROR(v, 0x122));   // row_ror:2
    v = fmaxf(v, DPPROR(v, 0x124));   // row_ror:4
    v = fmaxf(v, DPPROR(v, 0x128));   // row_ror:8
    return v;
}
__device__ __forceinline__ float rowsum16(float v) {
    v += DPPROR(v, 0x121);
    v += DPPROR(v, 0x122);
    v += DPPROR(v, 0x124);
    v += DPPROR(v, 0x128);
    return v;
}

// ---------------------------------------------------------------- RevIN stats
__global__ __launch_bounds__(256) void revin_stats_kernel(
        const float* __restrict__ x, float* __restrict__ mean, float* __restrict__ stdd) {
    int blk = blockIdx.x;            // b*16 + ntile
    int b = blk >> 4;
    int n0 = (blk & 15) << 6;
    int t = threadIdx.x;
    int ni = t & 63, sg = t >> 6;
    float s = 0.f, ss = 0.f;
    for (int sidx = sg; sidx < SEQ; sidx += 4) {
        float v = x[((size_t)b*SEQ + sidx)*NVAR + n0 + ni];
        s += v; ss += v*v;
    }
    __shared__ float rs[4][64], rq[4][64];
    rs[sg][ni] = s; rq[sg][ni] = ss;
    __syncthreads();
    if (t < 64) {
        float su = rs[0][t] + rs[1][t] + rs[2][t] + rs[3][t];
        float sq = rq[0][t] + rq[1][t] + rq[2][t] + rq[3][t];
        float m  = su / (float)SEQ;
        float var = sq / (float)SEQ - m*m;
        int n = n0 + t;
        mean[b*NVAR + n] = m;
        stdd[b*NVAR + n] = sqrtf(var + LN_EPS);
    }
}

// ------------------------------- RevIN normalize + transpose (split f16 out)
__global__ __launch_bounds__(256) void revin_norm_kernel(
        const float* __restrict__ x, const float* __restrict__ mean, const float* __restrict__ stdd,
        const float* __restrict__ rw, const float* __restrict__ rb,
        _Float16* __restrict__ xnhi, _Float16* __restrict__ xnlo) {
    __shared__ float tile[32][33];
    int n0 = blockIdx.x << 5, s0 = blockIdx.y << 5, b = blockIdx.z;
    int t = threadIdx.x;
    int j = t & 31, i0 = t >> 5;
    for (int ii = i0; ii < 32; ii += 8)
        tile[ii][j] = x[((size_t)b*SEQ + s0 + ii)*NVAR + n0 + j];
    __syncthreads();
    int si = t & 31, j0 = t >> 5;
    for (int nj = j0; nj < 32; nj += 8) {
        int n = n0 + nj;
        float m = mean[b*NVAR + n], sd = stdd[b*NVAR + n];
        float v = (tile[si][nj] - m) / sd * rw[n] + rb[n];
        _Float16 h_, l_; fsplit(v, h_, l_);
        size_t idx = ((size_t)b*NVAR + n)*SEQ + s0 + si;
        xnhi[idx] = h_; xnlo[idx] = l_;
    }
}

// ----------------------- weight transpose+split: [K,N] -> [N,K] f16 hi/lo
struct WSrcs { const float* p[9]; };
__global__ __launch_bounds__(256) void transpose_w_kernel(
        WSrcs srcs, _Float16* __restrict__ whi, _Float16* __restrict__ wlo) {
    const float* W = srcs.p[blockIdx.z];
    _Float16* oh = whi + (size_t)blockIdx.z * DM * DM;
    _Float16* ol = wlo + (size_t)blockIdx.z * DM * DM;
    __shared__ float tile[64][65];
    int k0 = blockIdx.x << 6, n0 = blockIdx.y << 6;
    int t = threadIdx.x;
    for (int idx = t; idx < 4096; idx += 256) {
        int k = idx >> 6, n = idx & 63;
        tile[k][n] = W[(size_t)(k0 + k)*DM + n0 + n];
    }
    __syncthreads();
    for (int idx = t; idx < 4096; idx += 256) {
        int n = idx >> 6, k = idx & 63;
        _Float16 h_, l_; fsplit(tile[k][n], h_, l_);
        size_t o = (size_t)(n0 + n)*DM + k0 + k;
        oh[o] = h_; ol[o] = l_;
    }
}

// ------------------------------------------- fp16x2 MFMA GEMM (fp32-grade)
// v6: 2-phase pipeline, global_load_lds staging, XCD swizzle.
__global__ __launch_bounds__(256) void gemm_f16x2_kernel(
        const _Float16* __restrict__ Ahg, const _Float16* __restrict__ Alg,
        const _Float16* __restrict__ Whg, const _Float16* __restrict__ Wlg,
        const float* __restrict__ bias, float* __restrict__ C,
        _Float16* __restrict__ Chi, _Float16* __restrict__ Clo,
        int M, int K, int N) {
    __shared__ _Float16 smem[24576];
    int id = blockIdx.x + (blockIdx.y << 3);       // grid (8,64), x fastest
    int rm = ((id & 7) << 6) | (id >> 3);          // bijective: xcd*64 + j
    int bm = (rm >> 3) << 7, bn = (rm & 7) << 6;
    int t = threadIdx.x;
    int w = t >> 6, lane = t & 63, m16 = lane & 15, quad = lane >> 4;
    int wv = __builtin_amdgcn_readfirstlane(w);
    int lrow = lane >> 2, lcol = (lane & 3) << 3;  // 4 lanes/row, 16B each
    f32x4 a1[2][4] = {}, a2[2][4] = {};

    #define G_STAGE(c, kk) do {                                              \
        _Pragma("unroll")                                                    \
        for (int ch = 0; ch < 2; ++ch) {                                     \
            size_t ga = (size_t)(bm + wv*32 + ch*16 + lrow)*K + (kk) + lcol; \
            gload_lds16(&Ahg[ga], &smem[(c)*4096 + (wv*32 + ch*16)*32]);     \
            gload_lds16(&Alg[ga], &smem[8192 + (c)*4096 + (wv*32 + ch*16)*32]); \
        }                                                                    \
        size_t gb = (size_t)(bn + wv*16 + lrow)*K + (kk) + lcol;             \
        gload_lds16(&Whg[gb], &smem[16384 + (c)*2048 + (wv*16)*32]);         \
        gload_lds16(&Wlg[gb], &smem[20480 + (c)*2048 + (wv*16)*32]);         \
    } while (0)

    G_STAGE(0, 0);
    int cur = 0;
    for (int k0 = 0; k0 < K; k0 += 32, cur ^= 1) {
        __syncthreads();
        if (k0 + 32 < K) G_STAGE(cur ^ 1, k0 + 32);
        const _Float16* AH = &smem[cur*4096];
        const _Float16* AL = &smem[8192 + cur*4096];
        const _Float16* BH = &smem[16384 + cur*2048];
        const _Float16* BL = &smem[20480 + cur*2048];
        f16x8 bh_[4], bl_[4];
#pragma unroll
        for (int nt = 0; nt < 4; ++nt) {
            bh_[nt] = *(const f16x8*)&BH[(nt*16 + m16)*32 + quad*8];
            bl_[nt] = *(const f16x8*)&BL[(nt*16 + m16)*32 + quad*8];
        }
#pragma unroll
        for (int h2 = 0; h2 < 2; ++h2) {
            f16x8 ah = *(const f16x8*)&AH[(w*32 + h2*16 + m16)*32 + quad*8];
            f16x8 al = *(const f16x8*)&AL[(w*32 + h2*16 + m16)*32 + quad*8];
#pragma unroll
            for (int nt = 0; nt < 4; ++nt) {
                a1[h2][nt] = MFMA16(ah, bh_[nt], a1[h2][nt], 0, 0, 0);
                a2[h2][nt] = MFMA16(ah, bl_[nt], a2[h2][nt], 0, 0, 0);
                a2[h2][nt] = MFMA16(al, bh_[nt], a2[h2][nt], 0, 0, 0);
            }
        }
    }
    #undef G_STAGE
#pragma unroll
    for (int h2 = 0; h2 < 2; ++h2)
#pragma unroll
        for (int nt = 0; nt < 4; ++nt) {
            int col = bn + nt*16 + m16;
            float bv = bias[col];
#pragma unroll
            for (int r = 0; r < 4; ++r) {
                size_t row = bm + w*32 + h2*16 + quad*4 + r;
                float v = a1[h2][nt][r] + a2[h2][nt][r]*ILSC + bv;
                if (C) C[row*N + col] = v;
                if (Chi) {
                    _Float16 h_, l_; fsplit(v, h_, l_);
                    Chi[row*N + col] = h_; Clo[row*N + col] = l_;
                }
            }
        }
}

// ---------------- merged Q+K+V projection: one dispatch, 1536 blocks.
// ids 0..1023: QK GEMM against [1024][512] packed Wq|Wk (contiguous planes);
// ids 1024..1535: V GEMM + transposed split output. Both read the same A,
// identical 48KB 2-phase staging; merging removes a launch + vt tail underfill.
__global__ __launch_bounds__(256) void gemm_qkvt_kernel(
        const _Float16* __restrict__ Ahg, const _Float16* __restrict__ Alg,
        const _Float16* __restrict__ Wqkh, const _Float16* __restrict__ Wqkl,
        const _Float16* __restrict__ Wvh,  const _Float16* __restrict__ Wvl,
        const float* __restrict__ biasQ, const float* __restrict__ biasK,
        const float* __restrict__ biasV,
        _Float16* __restrict__ Qhi, _Float16* __restrict__ Qlo,
        _Float16* __restrict__ KKhi, _Float16* __restrict__ KKlo,
        _Float16* __restrict__ vthi, _Float16* __restrict__ vtlo) {
    __shared__ _Float16 smem[24576];
    int t = threadIdx.x;
    int w = t >> 6, lane = t & 63, m16 = lane & 15, quad = lane >> 4;
    int wv = __builtin_amdgcn_readfirstlane(w);
    int lrow = lane >> 2, lcol = (lane & 3) << 3;

    if (blockIdx.x < 1024) {
        // ---------------- QK path ----------------
        int id = blockIdx.x;
        int rm = ((id & 7) << 7) | (id >> 3);          // xcd*128 + j
        int bm = (rm >> 4) << 7, bn = (rm & 15) << 6;  // 64 row x 16 col tiles
        f32x4 a1[2][4] = {}, a2[2][4] = {};
        #define QK_STAGE(c, kk) do {                                             \
            _Pragma("unroll")                                                    \
            for (int ch = 0; ch < 2; ++ch) {                                     \
                size_t ga = (size_t)(bm + wv*32 + ch*16 + lrow)*DM + (kk) + lcol;\
                gload_lds16(&Ahg[ga], &smem[(c)*4096 + (wv*32 + ch*16)*32]);     \
                gload_lds16(&Alg[ga], &smem[8192 + (c)*4096 + (wv*32 + ch*16)*32]); \
            }                                                                    \
            size_t gb = (size_t)(bn + wv*16 + lrow)*DM + (kk) + lcol;            \
            gload_lds16(&Wqkh[gb], &smem[16384 + (c)*2048 + (wv*16)*32]);        \
            gload_lds16(&Wqkl[gb], &smem[20480 + (c)*2048 + (wv*16)*32]);        \
        } while (0)
        QK_STAGE(0, 0);
        int cur = 0;
        for (int k0 = 0; k0 < DM; k0 += 32, cur ^= 1) {
            __syncthreads();
            if (k0 + 32 < DM) QK_STAGE(cur ^ 1, k0 + 32);
            const _Float16* AH = &smem[cur*4096];
            const _Float16* AL = &smem[8192 + cur*4096];
            const _Float16* BH = &smem[16384 + cur*2048];
            const _Float16* BL = &smem[20480 + cur*2048];
            f16x8 bh_[4], bl_[4];
#pragma unroll
            for (int nt = 0; nt < 4; ++nt) {
                bh_[nt] = *(const f16x8*)&BH[(nt*16 + m16)*32 + quad*8];
                bl_[nt] = *(const f16x8*)&BL[(nt*16 + m16)*32 + quad*8];
            }
#pragma unroll
            for (int h2 = 0; h2 < 2; ++h2) {
                f16x8 ah = *(const f16x8*)&AH[(w*32 + h2*16 + m16)*32 + quad*8];
                f16x8 al = *(const f16x8*)&AL[(w*32 + h2*16 + m16)*32 + quad*8];
#pragma unroll
                for (int nt = 0; nt < 4; ++nt) {
                    a1[h2][nt] = MFMA16(ah, bh_[nt], a1[h2][nt], 0, 0, 0);
                    a2[h2][nt] = MFMA16(ah, bl_[nt], a2[h2][nt], 0, 0, 0);
                    a2[h2][nt] = MFMA16(al, bh_[nt], a2[h2][nt], 0, 0, 0);
                }
            }
        }
        #undef QK_STAGE
        const float* bias = (bn < 512) ? biasQ : biasK;
        _Float16* Ohi = (bn < 512) ? Qhi : KKhi;
        _Float16* Olo = (bn < 512) ? Qlo : KKlo;
        int cb = (bn < 512) ? bn : bn - 512;
#pragma unroll
        for (int h2 = 0; h2 < 2; ++h2)
#pragma unroll
            for (int nt = 0; nt < 4; ++nt) {
                int col = cb + nt*16 + m16;
                float bv = bias[col];
#pragma unroll
                for (int r = 0; r < 4; ++r) {
                    size_t row = bm + w*32 + h2*16 + quad*4 + r;
                    float v = a1[h2][nt][r] + a2[h2][nt][r]*ILSC + bv;
                    _Float16 h_, l_; fsplit(v, h_, l_);
                    Ohi[row*DM + col] = h_; Olo[row*DM + col] = l_;
                }
            }
        return;
    }
    // ---------------- VT path ----------------
    {
        int id = blockIdx.x - 1024;
        int rm = ((id & 7) << 6) | (id >> 3);
        int bm = (rm >> 3) << 7, bn = (rm & 7) << 6;
        f32x4 a1[2][4] = {}, a2[2][4] = {};
        #define VT_STAGE(c, kk) do {                                             \
            _Pragma("unroll")                                                    \
            for (int ch = 0; ch < 2; ++ch) {                                     \
                size_t ga = (size_t)(bm + wv*32 + ch*16 + lrow)*DM + (kk) + lcol;\
                gload_lds16(&Ahg[ga], &smem[(c)*4096 + (wv*32 + ch*16)*32]);     \
                gload_lds16(&Alg[ga], &smem[8192 + (c)*4096 + (wv*32 + ch*16)*32]); \
            }                                                                    \
            size_t gb = (size_t)(bn + wv*16 + lrow)*DM + (kk) + lcol;            \
            gload_lds16(&Wvh[gb], &smem[16384 + (c)*2048 + (wv*16)*32]);         \
            gload_lds16(&Wvl[gb], &smem[20480 + (c)*2048 + (wv*16)*32]);         \
        } while (0)
        VT_STAGE(0, 0);
        int cur = 0;
        for (int k0 = 0; k0 < DM; k0 += 32, cur ^= 1) {
            __syncthreads();
            if (k0 + 32 < DM) VT_STAGE(cur ^ 1, k0 + 32);
            const _Float16* AH = &smem[cur*4096];
            const _Float16* AL = &smem[8192 + cur*4096];
            const _Float16* BH = &smem[16384 + cur*2048];
            const _Float16* BL = &smem[20480 + cur*2048];
            f16x8 bh_[4], bl_[4];
#pragma unroll
            for (int nt = 0; nt < 4; ++nt) {
                bh_[nt] = *(const f16x8*)&BH[(nt*16 + m16)*32 + quad*8];
                bl_[nt] = *(const f16x8*)&BL[(nt*16 + m16)*32 + quad*8];
            }
#pragma unroll
            for (int h2 = 0; h2 < 2; ++h2) {
                f16x8 ah = *(const f16x8*)&AH[(w*32 + h2*16 + m16)*32 + quad*8];
                f16x8 al = *(const f16x8*)&AL[(w*32 + h2*16 + m16)*32 + quad*8];
#pragma unroll
                for (int nt = 0; nt < 4; ++nt) {
                    a1[h2][nt] = MFMA16(ah, bh_[nt], a1[h2][nt], 0, 0, 0);
                    a2[h2][nt] = MFMA16(ah, bl_[nt], a2[h2][nt], 0, 0, 0);
                    a2[h2][nt] = MFMA16(al, bh_[nt], a2[h2][nt], 0, 0, 0);
                }
            }
        }
        #undef VT_STAGE
        __syncthreads();                 // staging smem dead: reuse as Ct
        float (*Ct)[65] = (float (*)[65])smem;
#pragma unroll
        for (int h2 = 0; h2 < 2; ++h2)
#pragma unroll
            for (int nt = 0; nt < 4; ++nt) {
                float bv = biasV[bn + nt*16 + m16];
#pragma unroll
                for (int r = 0; r < 4; ++r)
                    Ct[w*32 + h2*16 + quad*4 + r][nt*16 + m16] = a1[h2][nt][r] + a2[h2][nt][r]*ILSC + bv;
            }
        __syncthreads();
        int b = bm >> 10, tokn0 = bm & 1023, hh = bn >> 6;
        int dh = t >> 2, tg = (t & 3) << 4;
        size_t rowb = ((size_t)(b*8 + hh)*64 + dh)*NVAR + tokn0;
        for (int hb = 0; hb < 2; ++hb) {
            int tl0 = hb*64 + tg;
            unsigned short hbuf[16], lbuf[16];
#pragma unroll
            for (int i = 0; i < 16; ++i) {
                _Float16 h_, l_; fsplit(Ct[tl0 + i][dh], h_, l_);
                hbuf[i] = __builtin_bit_cast(unsigned short, h_);
                lbuf[i] = __builtin_bit_cast(unsigned short, l_);
            }
            uint4 uh0, uh1, ul0, ul1;
            uh0.x = hbuf[0]|(hbuf[1]<<16);  uh0.y = hbuf[2]|(hbuf[3]<<16);
            uh0.z = hbuf[4]|(hbuf[5]<<16);  uh0.w = hbuf[6]|(hbuf[7]<<16);
            uh1.x = hbuf[8]|(hbuf[9]<<16);  uh1.y = hbuf[10]|(hbuf[11]<<16);
            uh1.z = hbuf[12]|(hbuf[13]<<16);uh1.w = hbuf[14]|(hbuf[15]<<16);
            ul0.x = lbuf[0]|(lbuf[1]<<16);  ul0.y = lbuf[2]|(lbuf[3]<<16);
            ul0.z = lbuf[4]|(lbuf[5]<<16);  ul0.w = lbuf[6]|(lbuf[7]<<16);
            ul1.x = lbuf[8]|(lbuf[9]<<16);  ul1.y = lbuf[10]|(lbuf[11]<<16);
            ul1.z = lbuf[12]|(lbuf[13]<<16);ul1.w = lbuf[14]|(lbuf[15]<<16);
            *(uint4*)&vthi[rowb + tl0]     = uh0;
            *(uint4*)&vthi[rowb + tl0 + 8] = uh1;
            *(uint4*)&vtlo[rowb + tl0]     = ul0;
            *(uint4*)&vtlo[rowb + tl0 + 8] = ul1;
        }
    }
}

// ------------------------------------- flash attention, fp16x2 MFMA
// v7 = v3 structure + Q-prescale + packed cvt_pkrtz splits (P and O).
__global__ __launch_bounds__(256, 4) void attn_f16x2_kernel(
        const _Float16* __restrict__ qh, const _Float16* __restrict__ ql,
        const _Float16* __restrict__ kh, const _Float16* __restrict__ kl,
        const _Float16* __restrict__ vth, const _Float16* __restrict__ vtl,
        _Float16* __restrict__ oh, _Float16* __restrict__ ol) {
    __shared__ _Float16 Kh[64][72], Kl[64][72];   // doubles as Ph/Pl after QK^T
    __shared__ _Float16 Vh[64][72], Vl[64][72];
    int blk = blockIdx.x;
    blk = ((blk & 7) << 7) | (blk >> 3);   // grid=1024: 128 consecutive work-blocks per XCD
    int qt = blk & 15, bh = blk >> 4;
    int b = bh >> 3, hh = bh & 7;
    int q0 = qt << 6;
    int t = threadIdx.x;
    int w = t >> 6, lane = t & 63;
    int m16 = lane & 15, quad = lane >> 4;
    size_t bbase = (size_t)b * NVAR;
    size_t vbase = (size_t)bh * DH * NVAR;

    f16x8 qfh[2], qfl[2];
#pragma unroll
    for (int ks = 0; ks < 2; ++ks) {
        size_t gq = (bbase + q0 + w*16 + m16)*DM + hh*DH + ks*32 + quad*8;
        qfh[ks] = *(const f16x8*)&qh[gq] * (_Float16)0.125f;
        qfl[ks] = *(const f16x8*)&ql[gq] * (_Float16)0.125f;
    }

    float mrow[4] = {-1e30f,-1e30f,-1e30f,-1e30f};
    float lrow[4] = {0.f,0.f,0.f,0.f};
    f32x4 o1[4] = {}, o2[4] = {};

    for (int n0 = 0; n0 < NVAR; n0 += 64) {
        for (int idx = t; idx < 512; idx += 256) {
            int r = idx >> 3, cg = (idx & 7) << 3;
            size_t gk = (bbase + n0 + r)*DM + hh*DH + cg;
            size_t gv = vbase + (size_t)r*NVAR + n0 + cg;
            *(uint4*)&Kh[r][cg] = *(const uint4*)&kh[gk];
            *(uint4*)&Kl[r][cg] = *(const uint4*)&kl[gk];
            *(uint4*)&Vh[r][cg] = *(const uint4*)&vth[gv];
            *(uint4*)&Vl[r][cg] = *(const uint4*)&vtl[gv];
        }
        __syncthreads();

        f32x4 s1[4] = {}, s2[4] = {};
#pragma unroll
        for (int ks = 0; ks < 2; ++ks) {
#pragma unroll
            for (int nt = 0; nt < 4; ++nt) {
                f16x8 bh_ = *(const f16x8*)&Kh[nt*16 + m16][ks*32 + quad*8];
                f16x8 bl_ = *(const f16x8*)&Kl[nt*16 + m16][ks*32 + quad*8];
                s1[nt] = MFMA16(qfh[ks], bh_, s1[nt], 0, 0, 0);
                s2[nt] = MFMA16(qfh[ks], bl_, s2[nt], 0, 0, 0);
                s2[nt] = MFMA16(qfl[ks], bh_, s2[nt], 0, 0, 0);
            }
        }
        __syncthreads();   // all waves done reading K: Kh/Kl reusable as P

        float pbuf[4][4];
        float mx[4];
#pragma unroll
        for (int r = 0; r < 4; ++r) {
            float sv0 = fmaf(s2[0][r], ILSC, s1[0][r]);
            float sv1 = fmaf(s2[1][r], ILSC, s1[1][r]);
            float sv2 = fmaf(s2[2][r], ILSC, s1[2][r]);
            float sv3 = fmaf(s2[3][r], ILSC, s1[3][r]);
            pbuf[0][r] = sv0; pbuf[1][r] = sv1; pbuf[2][r] = sv2; pbuf[3][r] = sv3;
            mx[r] = rowmax16(fmaxf(fmaxf(sv0, sv1), fmaxf(sv2, sv3)));
        }
        bool grow = (mx[0] > mrow[0]) | (mx[1] > mrow[1]) |
                    (mx[2] > mrow[2]) | (mx[3] > mrow[3]);
        if (__any(grow)) {
#pragma unroll
            for (int r = 0; r < 4; ++r) {
                float mnew = fmaxf(mrow[r], mx[r]);
                float alpha = __expf(mrow[r] - mnew);
                mrow[r] = mnew;
                lrow[r] *= alpha;
#pragma unroll
                for (int nt = 0; nt < 4; ++nt) { o1[nt][r] *= alpha; o2[nt][r] *= alpha; }
            }
        }
#pragma unroll
        for (int r = 0; r < 4; ++r) {
            float p0 = __expf(pbuf[0][r] - mrow[r]);
            float p1 = __expf(pbuf[1][r] - mrow[r]);
            float p2 = __expf(pbuf[2][r] - mrow[r]);
            float p3 = __expf(pbuf[3][r] - mrow[r]);
            lrow[r] += rowsum16(p0 + p1 + p2 + p3);
            pbuf[0][r] = p0; pbuf[1][r] = p1; pbuf[2][r] = p2; pbuf[3][r] = p3;
        }
        // P -> LDS (into dead K tile), packed cvt. Intra-wave RAW via lgkmcnt.
#pragma unroll
        for (int nt = 0; nt < 4; ++nt)
#pragma unroll
            for (int rp = 0; rp < 2; ++rp) {
                f16x2 h2, l2;
                fsplit2(pbuf[nt][2*rp], pbuf[nt][2*rp + 1], h2, l2);
                Kh[w*16 + quad*4 + 2*rp][nt*16 + m16]     = h2.x;
                Kh[w*16 + quad*4 + 2*rp + 1][nt*16 + m16] = h2.y;
                Kl[w*16 + quad*4 + 2*rp][nt*16 + m16]     = l2.x;
                Kl[w*16 + quad*4 + 2*rp + 1][nt*16 + m16] = l2.y;
            }

#pragma unroll
        for (int ks = 0; ks < 2; ++ks) {
            f16x8 ph = *(const f16x8*)&Kh[w*16 + m16][ks*32 + quad*8];
            f16x8 pl = *(const f16x8*)&Kl[w*16 + m16][ks*32 + quad*8];
#pragma unroll
            for (int nt = 0; nt < 4; ++nt) {
                f16x8 vh_ = *(const f16x8*)&Vh[nt*16 + m16][ks*32 + quad*8];
                f16x8 vl_ = *(const f16x8*)&Vl[nt*16 + m16][ks*32 + quad*8];
                o1[nt] = MFMA16(ph, vh_, o1[nt], 0, 0, 0);
                o2[nt] = MFMA16(ph, vl_, o2[nt], 0, 0, 0);
                o2[nt] = MFMA16(pl, vh_, o2[nt], 0, 0, 0);
            }
        }
        __syncthreads();
    }
#pragma unroll
    for (int r = 0; r < 4; ++r) {
        float inv = 1.0f / lrow[r];
        size_t rowp = (bbase + q0 + w*16 + quad*4 + r)*DM + hh*DH;
        float ovv[4];
#pragma unroll
        for (int nt = 0; nt < 4; ++nt)
            ovv[nt] = fmaf(o2[nt][r], ILSC, o1[nt][r]) * inv;
#pragma unroll
        for (int np = 0; np < 2; ++np) {
            f16x2 h2, l2;
            fsplit2(ovv[2*np], ovv[2*np + 1], h2, l2);
            oh[rowp + (2*np)*16 + m16]     = h2.x;
            oh[rowp + (2*np + 1)*16 + m16] = h2.y;
            ol[rowp + (2*np)*16 + m16]     = l2.x;
            ol[rowp + (2*np + 1)*16 + m16] = l2.y;
        }
    }
}

// ---------------------------------------------------------------- LayerNorm
__global__ __launch_bounds__(256) void ln_kernel(
        _Float16* __restrict__ hhi, _Float16* __restrict__ hlo,
        const float* __restrict__ res,
        const float* __restrict__ w, const float* __restrict__ b) {
    int rowi = blockIdx.x, t = threadIdx.x;
    size_t base = (size_t)rowi * DM;
    int c = t << 1;
    f16x2 hv = *(const f16x2*)&hhi[base + c];
    f16x2 lv = *(const f16x2*)&hlo[base + c];
    float v0 = frec(hv.x, lv.x);
    float v1 = frec(hv.y, lv.y);
    if (res) { float2 rv = *(const float2*)&res[base + c]; v0 += rv.x; v1 += rv.y; }
    float s = v0 + v1, q = v0*v0 + v1*v1;
#pragma unroll
    for (int off = 1; off < 64; off <<= 1) {
        s += __shfl_xor(s, off);
        q += __shfl_xor(q, off);
    }
    __shared__ float sred[4], qred[4];
    int wid = t >> 6, lane = t & 63;
    if (lane == 0) { sred[wid] = s; qred[wid] = q; }
    __syncthreads();
    s = sred[0] + sred[1] + sred[2] + sred[3];
    q = qred[0] + qred[1] + qred[2] + qred[3];
    float m = s / (float)DM;
    float var = q / (float)DM - m*m;
    float inv = 1.0f / sqrtf(var + LN_EPS);
    float2 wv = *(const float2*)&w[c];
    float2 bv = *(const float2*)&b[c];
    float y0 = (v0 - m)*inv * wv.x + bv.x;
    float y1 = (v1 - m)*inv * wv.y + bv.y;
    f16x2 h2, l2; fsplit2(y0, y1, h2, l2);
    *(f16x2*)&hhi[base + c] = h2;
    *(f16x2*)&hlo[base + c] = l2;
}

__device__ __forceinline__ float gelu_exact(float xv) {
    return 0.5f * xv * (1.0f + erff(xv * 0.70710678118654752f));
}

// --------------------------------------- MoE FFN + fused LayerNorm (ln2)
__global__ __launch_bounds__(256) void moe_ln_kernel(
        _Float16* __restrict__ hhi, _Float16* __restrict__ hlo,
        const float* __restrict__ gW, const float* __restrict__ W1, const float* __restrict__ b1,
        const float* __restrict__ W2, const float* __restrict__ b2,
        const float* __restrict__ lw, const float* __restrict__ lb) {
    int tok = blockIdx.x, t = threadIdx.x;
    __shared__ float hs[DM];
    __shared__ float red[32][8];
    __shared__ float glog[8];
    __shared__ float hmid[8];
    __shared__ float wsel[2];
    __shared__ int   esel[2];
    __shared__ float sred[4], qred[4];
    size_t base = (size_t)tok * DM;
    int c = t << 1;
    f16x2 hv = *(const f16x2*)&hhi[base + c];
    f16x2 lv = *(const f16x2*)&hlo[base + c];
    float hv0 = frec(hv.x, lv.x);
    float hv1 = frec(hv.y, lv.y);
    hs[c] = hv0; hs[c + 1] = hv1;
    __syncthreads();
    int e = t & 7, i0 = t >> 3;
    {
        float a = 0.f;
        for (int i = i0; i < DM; i += 32) a += hs[i] * gW[i*NE + e];
        red[i0][e] = a;
    }
    __syncthreads();
    if (t < 8) { float sv = 0.f; for (int i = 0; i < 32; ++i) sv += red[i][t]; glog[t] = sv; }
    __syncthreads();
    if (t == 0) {
        float m0 = -1e30f, m1 = -1e30f; int s0i = 0, s1i = 0;
        for (int ei = 0; ei < 8; ++ei) {
            float vv = glog[ei];
            if (vv > m0) { m1 = m0; s1i = s0i; m0 = vv; s0i = ei; }
            else if (vv > m1) { m1 = vv; s1i = ei; }
        }
        float Z = 0.f;
        for (int ei = 0; ei < 8; ++ei) Z += expf(glog[ei] - m0);
        wsel[0] = 1.0f / Z;
        wsel[1] = expf(m1 - m0) / Z;
        esel[0] = s0i; esel[1] = s1i;
    }
    __syncthreads();
    float o0 = 0.f, o1 = 0.f;
    for (int ks = 0; ks < 2; ++ks) {
        int ee = esel[ks]; float wk = wsel[ks];
        int f = t & 7;
        float a = 0.f;
        for (int i = i0; i < DM; i += 32) a += hs[i] * W1[((size_t)ee*DM + i)*NF + f];
        red[i0][f] = a;
        __syncthreads();
        if (t < 8) {
            float sv = b1[ee*NF + t];
            for (int i = 0; i < 32; ++i) sv += red[i][t];
            hmid[t] = gelu_exact(sv);
        }
        __syncthreads();
        float2 b2v = *(const float2*)&b2[ee*DM + c];
        float s0v = b2v.x, s1v = b2v.y;
#pragma unroll
        for (int i = 0; i < NF; ++i) {
            float hm = hmid[i];
            float2 wpv = *(const float2*)&W2[((size_t)ee*NF + i)*DM + c];
            s0v += hm * wpv.x; s1v += hm * wpv.y;
        }
        o0 += wk * s0v; o1 += wk * s1v;
        __syncthreads();
    }
    // fused ln2: v = h + ffn
    float v0 = hv0 + o0, v1 = hv1 + o1;
    float s = v0 + v1, q = v0*v0 + v1*v1;
#pragma unroll
    for (int off = 1; off < 64; off <<= 1) {
        s += __shfl_xor(s, off);
        q += __shfl_xor(q, off);
    }
    int wid = t >> 6, lane = t & 63;
    if (lane == 0) { sred[wid] = s; qred[wid] = q; }
    __syncthreads();
    s = sred[0] + sred[1] + sred[2] + sred[3];
    q = qred[0] + qred[1] + qred[2] + qred[3];
    float m = s / (float)DM;
    float var = q / (float)DM - m*m;
    float inv = 1.0f / sqrtf(var + LN_EPS);
    float2 wv = *(const float2*)&lw[c];
    float2 bv = *(const float2*)&lb[c];
    float y0 = (v0 - m)*inv * wv.x + bv.x;
    float y1 = (v1 - m)*inv * wv.y + bv.y;
    f16x2 h2o, l2o; fsplit2(y0, y1, h2o, l2o);
    *(f16x2*)&hhi[base + c] = h2o;
    *(f16x2*)&hlo[base + c] = l2o;
}

// --------------------------- fused final LayerNorm + head gate (top-2 MoE)
// block 0 also zeroes cnt[0..7] (head_init folded in; stream order
// guarantees completion before head_bucket).
__global__ __launch_bounds__(256) void encln_gate_kernel(
        _Float16* __restrict__ hhi, _Float16* __restrict__ hlo,
        const float* __restrict__ lw, const float* __restrict__ lb,
        const float* __restrict__ gW,
        int* __restrict__ sel, float2* __restrict__ wpair,
        int* __restrict__ cnt) {
    int tok = blockIdx.x, t = threadIdx.x;
    if (tok == 0 && t < NE) cnt[t] = 0;
    __shared__ float hs[DM];
    __shared__ float red[32][8];
    __shared__ float glog[8];
    __shared__ float sred[4], qred[4];
    size_t base = (size_t)tok * DM;
    int c = t << 1;
    f16x2 hv = *(const f16x2*)&hhi[base + c];
    f16x2 lv = *(const f16x2*)&hlo[base + c];
    float v0 = frec(hv.x, lv.x);
    float v1 = frec(hv.y, lv.y);
    float s = v0 + v1, q = v0*v0 + v1*v1;
#pragma unroll
    for (int off = 1; off < 64; off <<= 1) {
        s += __shfl_xor(s, off);
        q += __shfl_xor(q, off);
    }
    int wid = t >> 6, lane = t & 63;
    if (lane == 0) { sred[wid] = s; qred[wid] = q; }
    __syncthreads();
    s = sred[0] + sred[1] + sred[2] + sred[3];
    q = qred[0] + qred[1] + qred[2] + qred[3];
    float m = s / (float)DM;
    float var = q / (float)DM - m*m;
    float inv = 1.0f / sqrtf(var + LN_EPS);
    float2 wv = *(const float2*)&lw[c];
    float2 bv = *(const float2*)&lb[c];
    float y0 = (v0 - m)*inv * wv.x + bv.x;
    float y1 = (v1 - m)*inv * wv.y + bv.y;
    f16x2 h2o, l2o; fsplit2(y0, y1, h2o, l2o);
    *(f16x2*)&hhi[base + c] = h2o;
    *(f16x2*)&hlo[base + c] = l2o;
    hs[c] = y0; hs[c + 1] = y1;
    __syncthreads();
    int e = t & 7, i0 = t >> 3;
    float a = 0.f;
    for (int i = i0; i < DM; i += 32) a += hs[i] * gW[i*NE + e];
    red[i0][e] = a;
    __syncthreads();
    if (t < 8) { float sv = 0.f; for (int i = 0; i < 32; ++i) sv += red[i][t]; glog[t] = sv; }
    __syncthreads();
    if (t == 0) {
        float m0 = -1e30f, m1 = -1e30f; int s0i = 0, s1i = 0;
        for (int ei = 0; ei < 8; ++ei) {
            float vv = glog[ei];
            if (vv > m0) { m1 = m0; s1i = s0i; m0 = vv; s0i = ei; }
            else if (vv > m1) { m1 = vv; s1i = ei; }
        }
        float Z = 0.f;
        for (int ei = 0; ei < 8; ++ei) Z += __expf(glog[ei] - m0);
        float2 wvv;
        wvv.x = 1.0f / Z;
        wvv.y = __expf(m1 - m0) / Z;
        sel[tok] = s0i | (s1i << 3);
        wpair[tok] = wvv;
    }
}

// ------------------------------------------------------------- head: bucket
__global__ __launch_bounds__(64) void head_bucket_kernel(
        const int* __restrict__ sel, const float2* __restrict__ wpair,
        int* __restrict__ cnt, int* __restrict__ idxlist, float* __restrict__ wlist,
        int* __restrict__ pos0, int* __restrict__ pos1) {
    int lane = threadIdx.x;
    int tok = blockIdx.x*64 + lane;
    int s = sel[tok];
    int s0 = s & 7, s1 = (s >> 3) & 7;
    float2 wv = wpair[tok];
    unsigned long long lmask = (lane == 63) ? 0x7FFFFFFFFFFFFFFFull
                                            : ((1ull << lane) - 1ull);
#pragma unroll
    for (int e = 0; e < NE; ++e) {
        unsigned long long m0 = __ballot(s0 == e);
        unsigned long long m1 = __ballot(s1 == e);
        int tot = __popcll(m0) + __popcll(m1);
        int basep = 0;
        if (lane == 0 && tot > 0) basep = atomicAdd(&cnt[e], tot);
        basep = __shfl(basep, 0);
        if (s0 == e) {
            int p = basep + __popcll(m0 & lmask);
            idxlist[e*NTOK + p] = tok; wlist[e*NTOK + p] = wv.x;
            pos0[tok] = (e << 16) | p;
        }
        if (s1 == e) {
            int p = basep + __popcll(m0) + __popcll(m1 & lmask);
            idxlist[e*NTOK + p] = tok; wlist[e*NTOK + p] = wv.y;
            pos1[tok] = (e << 16) | p;
        }
    }
}

// ------------------------------------------------------------- head: prefix
__global__ __launch_bounds__(64) void head_prefix_kernel(int* __restrict__ cnt) {
    if (threadIdx.x == 0) {
        int run = 0, trun = 0;
        for (int e = 0; e < NE; ++e) {
            cnt[8 + e]  = run;  run  += cnt[e];
            cnt[16 + e] = trun; trun += (cnt[e] + 63) >> 6;
        }
        cnt[24] = trun;
    }
}

// --------------------------------------------- head: grouped GEMM, fp16x2 MFMA
__global__ __launch_bounds__(256) void head_gemm_f16x2_kernel(
        const _Float16* __restrict__ hhi, const _Float16* __restrict__ hlo,
        const _Float16* __restrict__ hwhi, const _Float16* __restrict__ hwlo,
        const float* __restrict__ Hb,
        const int* __restrict__ cnt, const int* __restrict__ idxlist,
        const float* __restrict__ wlist, float* __restrict__ slotf) {
    int item = blockIdx.x;
    int total = cnt[24];
    if (item >= 2*total) return;
    int bn   = (item & 1) << 8;          // 0 or 256
    int tile = item >> 1;
    int e = 0;
#pragma unroll
    for (int ei = 1; ei < NE; ++ei) if (tile >= cnt[16 + ei]) e = ei;
    int m0 = (tile - cnt[16 + e]) << 6;
    int cnt_e = cnt[e];
    int rv = cnt_e - m0; if (rv > 64) rv = 64;
    int pref_e = cnt[8 + e];
    int t = threadIdx.x;
    int w = t >> 6, lane = t & 63, m16 = lane & 15, quad = lane >> 4;

    __shared__ _Float16 sAh[64][40], sAl[64][40];
    __shared__ _Float16 sBh[256][40], sBl[256][40];
    __shared__ int   idxs[64];
    __shared__ float ws[64];
    if (t < 64) {
        if (t < rv) { idxs[t] = idxlist[e*NTOK + m0 + t]; ws[t] = wlist[e*NTOK + m0 + t]; }
        else        { idxs[t] = idxlist[e*NTOK + m0];     ws[t] = 0.f; }
    }
    __syncthreads();

    const _Float16* Wh = hwhi + (size_t)e*DM*DM;
    const _Float16* Wl = hwlo + (size_t)e*DM*DM;
    int ra = t >> 2, ca = (t & 3) << 3;   // 4 lanes/row, 8 f16 (16B) each
    f32x4 a1[4][4] = {}, a2[4][4] = {};   // [mtile][ntile]
    for (int k0 = 0; k0 < DM; k0 += 32) {
        size_t ga = (size_t)idxs[ra]*DM + k0 + ca;
        *(uint4*)&sAh[ra][ca] = *(const uint4*)&hhi[ga];
        *(uint4*)&sAl[ra][ca] = *(const uint4*)&hlo[ga];
#pragma unroll
        for (int p = 0; p < 4; ++p) {
            int rb = p*64 + ra;
            size_t gb = (size_t)(bn + rb)*DM + k0 + ca;
            *(uint4*)&sBh[rb][ca] = *(const uint4*)&Wh[gb];
            *(uint4*)&sBl[rb][ca] = *(const uint4*)&Wl[gb];
        }
        __syncthreads();
        f16x8 ah[4], al[4];
#pragma unroll
        for (int mt = 0; mt < 4; ++mt) {
            ah[mt] = *(const f16x8*)&sAh[mt*16 + m16][quad*8];
            al[mt] = *(const f16x8*)&sAl[mt*16 + m16][quad*8];
        }
#pragma unroll
        for (int nt = 0; nt < 4; ++nt) {
            f16x8 bh_ = *(const f16x8*)&sBh[w*64 + nt*16 + m16][quad*8];
            f16x8 bl_ = *(const f16x8*)&sBl[w*64 + nt*16 + m16][quad*8];
#pragma unroll
            for (int mt = 0; mt < 4; ++mt) {
                a1[mt][nt] = MFMA16(ah[mt], bh_, a1[mt][nt], 0, 0, 0);
                a2[mt][nt] = MFMA16(ah[mt], bl_, a2[mt][nt], 0, 0, 0);
                a2[mt][nt] = MFMA16(al[mt], bh_, a2[mt][nt], 0, 0, 0);
            }
        }
        __syncthreads();
    }
#pragma unroll
    for (int mt = 0; mt < 4; ++mt)
#pragma unroll
        for (int r = 0; r < 4; ++r) {
            int rloc = mt*16 + quad*4 + r;
            if (rloc < rv) {
                float wk = ws[rloc];
                size_t srow = (size_t)(pref_e + m0 + rloc)*DM;
#pragma unroll
                for (int nt = 0; nt < 4; ++nt) {
                    int gcol = bn + w*64 + nt*16 + m16;
                    float v = a1[mt][nt][r] + a2[mt][nt][r]*ILSC + Hb[e*DM + gcol];
                    slotf[srow + gcol] = wk * v;
                }
            }
        }
}

// ------------------------------------------------------------- head: combine+denorm
__global__ __launch_bounds__(256) void head_combine_kernel(
        const float* __restrict__ slotf,
        const int* __restrict__ pos0, const int* __restrict__ pos1,
        const int* __restrict__ cnt,
        const float* __restrict__ rw, const float* __restrict__ rb,
        const float* __restrict__ mean, const float* __restrict__ stdd,
        float* __restrict__ out) {
    int tok = blockIdx.x, t = threadIdx.x;
    int n = tok & (NVAR - 1);
    int e0enc = pos0[tok], e1enc = pos1[tok];
    size_t s0 = (size_t)(cnt[8 + (e0enc >> 16)] + (e0enc & 0xFFFF)) * DM;
    size_t s1 = (size_t)(cnt[8 + (e1enc >> 16)] + (e1enc & 0xFFFF)) * DM;
    size_t base = (size_t)tok * DM;
    float mn = mean[tok], sd = stdd[tok];
    float rwv = rw[n] + 1e-10f, rbv = rb[n];
    float o0 = slotf[s0 + t] + slotf[s1 + t];
    float o1 = slotf[s0 + t + 256] + slotf[s1 + t + 256];
    out[base + t]       = (o0 - rbv) / rwv * sd + mn;
    out[base + t + 256] = (o1 - rbv) / rwv * sd + mn;
}

// ---------------------------------------------------------------- launch
extern "C" void kernel_launch(void* const* d_in, const int* in_sizes, int n_in,
                              void* d_out, int out_size, void* d_ws, size_t ws_size,
                              hipStream_t stream) {
    const float* x       = (const float*)d_in[0];
    const float* revin_w = (const float*)d_in[1];
    const float* revin_b = (const float*)d_in[2];
    const float* emb_W   = (const float*)d_in[3];
    const float* emb_b   = (const float*)d_in[4];
    const float* Wq      = (const float*)d_in[5];
    const float* bq      = (const float*)d_in[6];
    const float* Wk      = (const float*)d_in[7];
    const float* bk      = (const float*)d_in[8];
    const float* Wv      = (const float*)d_in[9];
    const float* bv      = (const float*)d_in[10];
    const float* Wo      = (const float*)d_in[11];
    const float* bo      = (const float*)d_in[12];
    const float* ln1_w   = (const float*)d_in[13];
    const float* ln1_b   = (const float*)d_in[14];
    const float* ln2_w   = (const float*)d_in[15];
    const float* ln2_b   = (const float*)d_in[16];
    const float* gate_W  = (const float*)d_in[17];
    const float* eW1     = (const float*)d_in[18];
    const float* eb1     = (const float*)d_in[19];
    const float* eW2     = (const float*)d_in[20];
    const float* eb2     = (const float*)d_in[21];
    const float* enc_w   = (const float*)d_in[22];
    const float* enc_b   = (const float*)d_in[23];
    const float* hgW     = (const float*)d_in[24];
    const float* hW      = (const float*)d_in[25];
    const float* hb      = (const float*)d_in[26];
    float* out = (float*)d_out;

    const size_t TOKD = (size_t)NTOK * DM;   // 4194304
    float* ws   = (float*)d_ws;
    float* mean = ws;
    float* stdd = ws + 8192;
    _Float16* hhi  = (_Float16*)(ws + 16384);
    _Float16* hlo  = hhi + TOKD;
    _Float16* qhi  = hlo + TOKD;     // head stage: slotf spans qhi..klo (32 MiB)
    _Float16* qlo  = qhi + TOKD;
    _Float16* khi  = qlo + TOKD;     // also proj fp32 raw
    _Float16* klo  = khi + TOKD;
    _Float16* vthi = klo + TOKD;     // head stage: head split weights (4 MB used)
    _Float16* vtlo = vthi + TOKD;
    _Float16* whi  = vtlo + TOKD;    // 9 transposed split weights
    _Float16* wlo  = whi + (size_t)9*DM*DM;
    int*   cnt     = (int*)(wlo + (size_t)9*DM*DM);   // [0..7]=cnt,[8..15]=tok prefix,[16..23]=tile prefix,[24]=total
    int*   idxlist = cnt + 32;
    float* wlist   = (float*)(idxlist + NE*NTOK);
    int*   sel     = (int*)(wlist + NE*NTOK);
    float2* wpair  = (float2*)(sel + NTOK);
    int*   pos0    = (int*)(wpair + NTOK);
    int*   pos1    = pos0 + NTOK;
    float* proj    = (float*)khi;
    float* slotf   = (float*)qhi;

    dim3 blk(256);
    dim3 ggemm(DM/64, NTOK/128);     // (8, 64)

    revin_stats_kernel<<<dim3(BATCH*16), blk, 0, stream>>>(x, mean, stdd);
    revin_norm_kernel<<<dim3(NVAR/32, SEQ/32, BATCH), blk, 0, stream>>>(
        x, mean, stdd, revin_w, revin_b, qhi, qlo);

    WSrcs srcs;
    srcs.p[0] = emb_W;
    for (int l = 0; l < NL; ++l) {
        srcs.p[1 + l*4 + 0] = Wq + (size_t)l*DM*DM;
        srcs.p[1 + l*4 + 1] = Wk + (size_t)l*DM*DM;
        srcs.p[1 + l*4 + 2] = Wv + (size_t)l*DM*DM;
        srcs.p[1 + l*4 + 3] = Wo + (size_t)l*DM*DM;
    }
    transpose_w_kernel<<<dim3(8, 8, 9), blk, 0, stream>>>(srcs, whi, wlo);

    gemm_f16x2_kernel<<<ggemm, blk, 0, stream>>>(
        qhi, qlo, whi, wlo, emb_b, nullptr, hhi, hlo, NTOK, SEQ, DM);

    for (int l = 0; l < NL; ++l) {
        size_t oq = (size_t)(1 + l*4 + 0)*DM*DM;   // Wq^T; Wk^T contiguous after
        size_t ov = (size_t)(1 + l*4 + 2)*DM*DM;
        size_t oo = (size_t)(1 + l*4 + 3)*DM*DM;
        gemm_qkvt_kernel<<<dim3(1536), blk, 0, stream>>>(
            hhi, hlo, whi + oq, wlo + oq, whi + ov, wlo + ov,
            bq + l*DM, bk + l*DM, bv + l*DM,
            qhi, qlo, khi, klo, vthi, vtlo);
        attn_f16x2_kernel<<<dim3(64*16), blk, 0, stream>>>(
            qhi, qlo, khi, klo, vthi, vtlo, qhi, qlo);
        gemm_f16x2_kernel<<<ggemm, blk, 0, stream>>>(
            qhi, qlo, whi + oo, wlo + oo, bo + l*DM, proj, nullptr, nullptr, NTOK, DM, DM);
        ln_kernel<<<dim3(NTOK), blk, 0, stream>>>(hhi, hlo, proj, ln1_w + l*DM, ln1_b + l*DM);
        moe_ln_kernel<<<dim3(NTOK), blk, 0, stream>>>(
            hhi, hlo, gate_W + (size_t)l*DM*NE,
            eW1 + (size_t)l*NE*DM*NF, eb1 + (size_t)l*NE*NF,
            eW2 + (size_t)l*NE*NF*DM, eb2 + (size_t)l*NE*DM,
            ln2_w + l*DM, ln2_b + l*DM);
    }

    // head expert weights -> split f16 in the (now dead) vt planes
    WSrcs hsrcs;
    for (int e = 0; e < NE; ++e) hsrcs.p[e] = hW + (size_t)e*DM*DM;
    hsrcs.p[8] = hW;   // unused
    transpose_w_kernel<<<dim3(8, 8, 8), blk, 0, stream>>>(hsrcs, vthi, vtlo);

    encln_gate_kernel<<<dim3(NTOK), blk, 0, stream>>>(
        hhi, hlo, enc_w, enc_b, hgW, sel, wpair, cnt);
    head_bucket_kernel<<<dim3(NTOK/64), dim3(64), 0, stream>>>(
        sel, wpair, cnt, idxlist, wlist, pos0, pos1);
    head_prefix_kernel<<<dim3(1), dim3(64), 0, stream>>>(cnt);
    // max tiles: 263 (one expert hoards all tokens) -> 2*263=526; pad to 576
    head_gemm_f16x2_kernel<<<dim3(576), blk, 0, stream>>>(
        hhi, hlo, vthi, vtlo, hb, cnt, idxlist, wlist, slotf);
    head_combine_kernel<<<dim3(NTOK), blk, 0, stream>>>(
        slotf, pos0, pos1, cnt, revin_w, revin_b, mean, stdd, out);
}

// Round 13
// 764.540 us; speedup vs baseline: 1.0640x; 1.0640x over previous
//
#include <hip/hip_runtime.h>
#include <math.h>

#define BATCH 8
#define SEQ 512
#define NVAR 1024
#define DM 512
#define NH 8
#define DH 64
#define NE 8
#define NF 8
#define NL 2
#define NTOK (BATCH*NVAR)   // 8192
#define LN_EPS 1e-5f
#define LSC 2048.0f
#define ILSC (1.0f/2048.0f)

typedef __attribute__((ext_vector_type(8))) _Float16 f16x8;
typedef __attribute__((ext_vector_type(2))) _Float16 f16x2;
typedef __attribute__((ext_vector_type(4))) float f32x4;
#define MFMA16 __builtin_amdgcn_mfma_f32_16x16x32_f16

__device__ __forceinline__ void fsplit(float v, _Float16& hi, _Float16& lo) {
    hi = (_Float16)v;
    lo = (_Float16)((v - (float)hi) * LSC);
}
__device__ __forceinline__ float frec(_Float16 hi, _Float16 lo) {
    return (float)hi + (float)lo * ILSC;
}
// packed split: 2 floats -> hi pair + lo pair (1 cvt instr each). RTZ on hi is
// compensated exactly by lo; reconstruction accuracy unchanged (~2^-22 rel).
__device__ __forceinline__ void fsplit2(float a, float b, f16x2& h2, f16x2& l2) {
    h2 = __builtin_bit_cast(f16x2, __builtin_amdgcn_cvt_pkrtz(a, b));
    l2 = __builtin_bit_cast(f16x2, __builtin_amdgcn_cvt_pkrtz(
             (a - (float)h2.x)*LSC, (b - (float)h2.y)*LSC));
}

// direct HBM->LDS, 16B/lane; LDS dest = wave-uniform base + lane*16 (linear).
// Global source address may be fully per-lane (gathers OK).
__device__ __forceinline__ void gload_lds16(const _Float16* g, _Float16* l) {
    __builtin_amdgcn_global_load_lds(
        (const __attribute__((address_space(1))) void*)g,
        (__attribute__((address_space(3))) void*)l, 16, 0, 0);
}

// DPP row-of-16 rotation reduce (VALU-only, off the DS pipe)
#define DPPROR(v, C) __int_as_float(__builtin_amdgcn_update_dpp(0, __float_as_int(v), (C), 0xF, 0xF, true))
__device__ __forceinline__ float rowmax16(float v) {
    v = fmaxf(v, DPPROR(v, 0x121));   // row_ror:1
    v = fmaxf(v, DPPROR(v, 0x122));   // row_ror:2
    v = fmaxf(v, DPPROR(v, 0x124));   // row_ror:4
    v = fmaxf(v, DPPROR(v, 0x128));   // row_ror:8
    return v;
}
__device__ __forceinline__ float rowsum16(float v) {
    v += DPPROR(v, 0x121);
    v += DPPROR(v, 0x122);
    v += DPPROR(v, 0x124);
    v += DPPROR(v, 0x128);
    return v;
}

// ---------------------------------------------------------------- RevIN stats
__global__ __launch_bounds__(256) void revin_stats_kernel(
        const float* __restrict__ x, float* __restrict__ mean, float* __restrict__ stdd) {
    int blk = blockIdx.x;            // b*16 + ntile
    int b = blk >> 4;
    int n0 = (blk & 15) << 6;
    int t = threadIdx.x;
    int ni = t & 63, sg = t >> 6;
    float s = 0.f, ss = 0.f;
    for (int sidx = sg; sidx < SEQ; sidx += 4) {
        float v = x[((size_t)b*SEQ + sidx)*NVAR + n0 + ni];
        s += v; ss += v*v;
    }
    __shared__ float rs[4][64], rq[4][64];
    rs[sg][ni] = s; rq[sg][ni] = ss;
    __syncthreads();
    if (t < 64) {
        float su = rs[0][t] + rs[1][t] + rs[2][t] + rs[3][t];
        float sq = rq[0][t] + rq[1][t] + rq[2][t] + rq[3][t];
        float m  = su / (float)SEQ;
        float var = sq / (float)SEQ - m*m;
        int n = n0 + t;
        mean[b*NVAR + n] = m;
        stdd[b*NVAR + n] = sqrtf(var + LN_EPS);
    }
}

// ------------------------------- RevIN normalize + transpose (split f16 out)
__global__ __launch_bounds__(256) void revin_norm_kernel(
        const float* __restrict__ x, const float* __restrict__ mean, const float* __restrict__ stdd,
        const float* __restrict__ rw, const float* __restrict__ rb,
        _Float16* __restrict__ xnhi, _Float16* __restrict__ xnlo) {
    __shared__ float tile[32][33];
    int n0 = blockIdx.x << 5, s0 = blockIdx.y << 5, b = blockIdx.z;
    int t = threadIdx.x;
    int j = t & 31, i0 = t >> 5;
    for (int ii = i0; ii < 32; ii += 8)
        tile[ii][j] = x[((size_t)b*SEQ + s0 + ii)*NVAR + n0 + j];
    __syncthreads();
    int si = t & 31, j0 = t >> 5;
    for (int nj = j0; nj < 32; nj += 8) {
        int n = n0 + nj;
        float m = mean[b*NVAR + n], sd = stdd[b*NVAR + n];
        float v = (tile[si][nj] - m) / sd * rw[n] + rb[n];
        _Float16 h_, l_; fsplit(v, h_, l_);
        size_t idx = ((size_t)b*NVAR + n)*SEQ + s0 + si;
        xnhi[idx] = h_; xnlo[idx] = l_;
    }
}

// ----------------------- weight transpose+split: [K,N] -> [N,K] f16 hi/lo
struct WSrcs { const float* p[9]; };
__global__ __launch_bounds__(256) void transpose_w_kernel(
        WSrcs srcs, _Float16* __restrict__ whi, _Float16* __restrict__ wlo) {
    const float* W = srcs.p[blockIdx.z];
    _Float16* oh = whi + (size_t)blockIdx.z * DM * DM;
    _Float16* ol = wlo + (size_t)blockIdx.z * DM * DM;
    __shared__ float tile[64][65];
    int k0 = blockIdx.x << 6, n0 = blockIdx.y << 6;
    int t = threadIdx.x;
    for (int idx = t; idx < 4096; idx += 256) {
        int k = idx >> 6, n = idx & 63;
        tile[k][n] = W[(size_t)(k0 + k)*DM + n0 + n];
    }
    __syncthreads();
    for (int idx = t; idx < 4096; idx += 256) {
        int n = idx >> 6, k = idx & 63;
        _Float16 h_, l_; fsplit(tile[k][n], h_, l_);
        size_t o = (size_t)(n0 + n)*DM + k0 + k;
        oh[o] = h_; ol[o] = l_;
    }
}

// ------------------------------------------- fp16x2 MFMA GEMM (fp32-grade)
// v6: 2-phase pipeline, global_load_lds staging, XCD swizzle.
__global__ __launch_bounds__(256) void gemm_f16x2_kernel(
        const _Float16* __restrict__ Ahg, const _Float16* __restrict__ Alg,
        const _Float16* __restrict__ Whg, const _Float16* __restrict__ Wlg,
        const float* __restrict__ bias, float* __restrict__ C,
        _Float16* __restrict__ Chi, _Float16* __restrict__ Clo,
        int M, int K, int N) {
    __shared__ _Float16 smem[24576];
    int id = blockIdx.x + (blockIdx.y << 3);       // grid (8,64), x fastest
    int rm = ((id & 7) << 6) | (id >> 3);          // bijective: xcd*64 + j
    int bm = (rm >> 3) << 7, bn = (rm & 7) << 6;
    int t = threadIdx.x;
    int w = t >> 6, lane = t & 63, m16 = lane & 15, quad = lane >> 4;
    int wv = __builtin_amdgcn_readfirstlane(w);
    int lrow = lane >> 2, lcol = (lane & 3) << 3;  // 4 lanes/row, 16B each
    f32x4 a1[2][4] = {}, a2[2][4] = {};

    #define G_STAGE(c, kk) do {                                              \
        _Pragma("unroll")                                                    \
        for (int ch = 0; ch < 2; ++ch) {                                     \
            size_t ga = (size_t)(bm + wv*32 + ch*16 + lrow)*K + (kk) + lcol; \
            gload_lds16(&Ahg[ga], &smem[(c)*4096 + (wv*32 + ch*16)*32]);     \
            gload_lds16(&Alg[ga], &smem[8192 + (c)*4096 + (wv*32 + ch*16)*32]); \
        }                                                                    \
        size_t gb = (size_t)(bn + wv*16 + lrow)*K + (kk) + lcol;             \
        gload_lds16(&Whg[gb], &smem[16384 + (c)*2048 + (wv*16)*32]);         \
        gload_lds16(&Wlg[gb], &smem[20480 + (c)*2048 + (wv*16)*32]);         \
    } while (0)

    G_STAGE(0, 0);
    int cur = 0;
    for (int k0 = 0; k0 < K; k0 += 32, cur ^= 1) {
        __syncthreads();
        if (k0 + 32 < K) G_STAGE(cur ^ 1, k0 + 32);
        const _Float16* AH = &smem[cur*4096];
        const _Float16* AL = &smem[8192 + cur*4096];
        const _Float16* BH = &smem[16384 + cur*2048];
        const _Float16* BL = &smem[20480 + cur*2048];
        f16x8 bh_[4], bl_[4];
#pragma unroll
        for (int nt = 0; nt < 4; ++nt) {
            bh_[nt] = *(const f16x8*)&BH[(nt*16 + m16)*32 + quad*8];
            bl_[nt] = *(const f16x8*)&BL[(nt*16 + m16)*32 + quad*8];
        }
#pragma unroll
        for (int h2 = 0; h2 < 2; ++h2) {
            f16x8 ah = *(const f16x8*)&AH[(w*32 + h2*16 + m16)*32 + quad*8];
            f16x8 al = *(const f16x8*)&AL[(w*32 + h2*16 + m16)*32 + quad*8];
#pragma unroll
            for (int nt = 0; nt < 4; ++nt) {
                a1[h2][nt] = MFMA16(ah, bh_[nt], a1[h2][nt], 0, 0, 0);
                a2[h2][nt] = MFMA16(ah, bl_[nt], a2[h2][nt], 0, 0, 0);
                a2[h2][nt] = MFMA16(al, bh_[nt], a2[h2][nt], 0, 0, 0);
            }
        }
    }
    #undef G_STAGE
#pragma unroll
    for (int h2 = 0; h2 < 2; ++h2)
#pragma unroll
        for (int nt = 0; nt < 4; ++nt) {
            int col = bn + nt*16 + m16;
            float bv = bias[col];
#pragma unroll
            for (int r = 0; r < 4; ++r) {
                size_t row = bm + w*32 + h2*16 + quad*4 + r;
                float v = a1[h2][nt][r] + a2[h2][nt][r]*ILSC + bv;
                if (C) C[row*N + col] = v;
                if (Chi) {
                    _Float16 h_, l_; fsplit(v, h_, l_);
                    Chi[row*N + col] = h_; Clo[row*N + col] = l_;
                }
            }
        }
}

// ---------------- merged Q+K+V projection: one dispatch, 1536 blocks.
__global__ __launch_bounds__(256) void gemm_qkvt_kernel(
        const _Float16* __restrict__ Ahg, const _Float16* __restrict__ Alg,
        const _Float16* __restrict__ Wqkh, const _Float16* __restrict__ Wqkl,
        const _Float16* __restrict__ Wvh,  const _Float16* __restrict__ Wvl,
        const float* __restrict__ biasQ, const float* __restrict__ biasK,
        const float* __restrict__ biasV,
        _Float16* __restrict__ Qhi, _Float16* __restrict__ Qlo,
        _Float16* __restrict__ KKhi, _Float16* __restrict__ KKlo,
        _Float16* __restrict__ vthi, _Float16* __restrict__ vtlo) {
    __shared__ _Float16 smem[24576];
    int t = threadIdx.x;
    int w = t >> 6, lane = t & 63, m16 = lane & 15, quad = lane >> 4;
    int wv = __builtin_amdgcn_readfirstlane(w);
    int lrow = lane >> 2, lcol = (lane & 3) << 3;

    if (blockIdx.x < 1024) {
        // ---------------- QK path ----------------
        int id = blockIdx.x;
        int rm = ((id & 7) << 7) | (id >> 3);          // xcd*128 + j
        int bm = (rm >> 4) << 7, bn = (rm & 15) << 6;  // 64 row x 16 col tiles
        f32x4 a1[2][4] = {}, a2[2][4] = {};
        #define QK_STAGE(c, kk) do {                                             \
            _Pragma("unroll")                                                    \
            for (int ch = 0; ch < 2; ++ch) {                                     \
                size_t ga = (size_t)(bm + wv*32 + ch*16 + lrow)*DM + (kk) + lcol;\
                gload_lds16(&Ahg[ga], &smem[(c)*4096 + (wv*32 + ch*16)*32]);     \
                gload_lds16(&Alg[ga], &smem[8192 + (c)*4096 + (wv*32 + ch*16)*32]); \
            }                                                                    \
            size_t gb = (size_t)(bn + wv*16 + lrow)*DM + (kk) + lcol;            \
            gload_lds16(&Wqkh[gb], &smem[16384 + (c)*2048 + (wv*16)*32]);        \
            gload_lds16(&Wqkl[gb], &smem[20480 + (c)*2048 + (wv*16)*32]);        \
        } while (0)
        QK_STAGE(0, 0);
        int cur = 0;
        for (int k0 = 0; k0 < DM; k0 += 32, cur ^= 1) {
            __syncthreads();
            if (k0 + 32 < DM) QK_STAGE(cur ^ 1, k0 + 32);
            const _Float16* AH = &smem[cur*4096];
            const _Float16* AL = &smem[8192 + cur*4096];
            const _Float16* BH = &smem[16384 + cur*2048];
            const _Float16* BL = &smem[20480 + cur*2048];
            f16x8 bh_[4], bl_[4];
#pragma unroll
            for (int nt = 0; nt < 4; ++nt) {
                bh_[nt] = *(const f16x8*)&BH[(nt*16 + m16)*32 + quad*8];
                bl_[nt] = *(const f16x8*)&BL[(nt*16 + m16)*32 + quad*8];
            }
#pragma unroll
            for (int h2 = 0; h2 < 2; ++h2) {
                f16x8 ah = *(const f16x8*)&AH[(w*32 + h2*16 + m16)*32 + quad*8];
                f16x8 al = *(const f16x8*)&AL[(w*32 + h2*16 + m16)*32 + quad*8];
#pragma unroll
                for (int nt = 0; nt < 4; ++nt) {
                    a1[h2][nt] = MFMA16(ah, bh_[nt], a1[h2][nt], 0, 0, 0);
                    a2[h2][nt] = MFMA16(ah, bl_[nt], a2[h2][nt], 0, 0, 0);
                    a2[h2][nt] = MFMA16(al, bh_[nt], a2[h2][nt], 0, 0, 0);
                }
            }
        }
        #undef QK_STAGE
        const float* bias = (bn < 512) ? biasQ : biasK;
        _Float16* Ohi = (bn < 512) ? Qhi : KKhi;
        _Float16* Olo = (bn < 512) ? Qlo : KKlo;
        int cb = (bn < 512) ? bn : bn - 512;
#pragma unroll
        for (int h2 = 0; h2 < 2; ++h2)
#pragma unroll
            for (int nt = 0; nt < 4; ++nt) {
                int col = cb + nt*16 + m16;
                float bv = bias[col];
#pragma unroll
                for (int r = 0; r < 4; ++r) {
                    size_t row = bm + w*32 + h2*16 + quad*4 + r;
                    float v = a1[h2][nt][r] + a2[h2][nt][r]*ILSC + bv;
                    _Float16 h_, l_; fsplit(v, h_, l_);
                    Ohi[row*DM + col] = h_; Olo[row*DM + col] = l_;
                }
            }
        return;
    }
    // ---------------- VT path ----------------
    {
        int id = blockIdx.x - 1024;
        int rm = ((id & 7) << 6) | (id >> 3);
        int bm = (rm >> 3) << 7, bn = (rm & 7) << 6;
        f32x4 a1[2][4] = {}, a2[2][4] = {};
        #define VT_STAGE(c, kk) do {                                             \
            _Pragma("unroll")                                                    \
            for (int ch = 0; ch < 2; ++ch) {                                     \
                size_t ga = (size_t)(bm + wv*32 + ch*16 + lrow)*DM + (kk) + lcol;\
                gload_lds16(&Ahg[ga], &smem[(c)*4096 + (wv*32 + ch*16)*32]);     \
                gload_lds16(&Alg[ga], &smem[8192 + (c)*4096 + (wv*32 + ch*16)*32]); \
            }                                                                    \
            size_t gb = (size_t)(bn + wv*16 + lrow)*DM + (kk) + lcol;            \
            gload_lds16(&Wvh[gb], &smem[16384 + (c)*2048 + (wv*16)*32]);         \
            gload_lds16(&Wvl[gb], &smem[20480 + (c)*2048 + (wv*16)*32]);         \
        } while (0)
        VT_STAGE(0, 0);
        int cur = 0;
        for (int k0 = 0; k0 < DM; k0 += 32, cur ^= 1) {
            __syncthreads();
            if (k0 + 32 < DM) VT_STAGE(cur ^ 1, k0 + 32);
            const _Float16* AH = &smem[cur*4096];
            const _Float16* AL = &smem[8192 + cur*4096];
            const _Float16* BH = &smem[16384 + cur*2048];
            const _Float16* BL = &smem[20480 + cur*2048];
            f16x8 bh_[4], bl_[4];
#pragma unroll
            for (int nt = 0; nt < 4; ++nt) {
                bh_[nt] = *(const f16x8*)&BH[(nt*16 + m16)*32 + quad*8];
                bl_[nt] = *(const f16x8*)&BL[(nt*16 + m16)*32 + quad*8];
            }
#pragma unroll
            for (int h2 = 0; h2 < 2; ++h2) {
                f16x8 ah = *(const f16x8*)&AH[(w*32 + h2*16 + m16)*32 + quad*8];
                f16x8 al = *(const f16x8*)&AL[(w*32 + h2*16 + m16)*32 + quad*8];
#pragma unroll
                for (int nt = 0; nt < 4; ++nt) {
                    a1[h2][nt] = MFMA16(ah, bh_[nt], a1[h2][nt], 0, 0, 0);
                    a2[h2][nt] = MFMA16(ah, bl_[nt], a2[h2][nt], 0, 0, 0);
                    a2[h2][nt] = MFMA16(al, bh_[nt], a2[h2][nt], 0, 0, 0);
                }
            }
        }
        #undef VT_STAGE
        __syncthreads();                 // staging smem dead: reuse as Ct
        float (*Ct)[65] = (float (*)[65])smem;
#pragma unroll
        for (int h2 = 0; h2 < 2; ++h2)
#pragma unroll
            for (int nt = 0; nt < 4; ++nt) {
                float bv = biasV[bn + nt*16 + m16];
#pragma unroll
                for (int r = 0; r < 4; ++r)
                    Ct[w*32 + h2*16 + quad*4 + r][nt*16 + m16] = a1[h2][nt][r] + a2[h2][nt][r]*ILSC + bv;
            }
        __syncthreads();
        int b = bm >> 10, tokn0 = bm & 1023, hh = bn >> 6;
        int dh = t >> 2, tg = (t & 3) << 4;
        size_t rowb = ((size_t)(b*8 + hh)*64 + dh)*NVAR + tokn0;
        for (int hb = 0; hb < 2; ++hb) {
            int tl0 = hb*64 + tg;
            unsigned short hbuf[16], lbuf[16];
#pragma unroll
            for (int i = 0; i < 16; ++i) {
                _Float16 h_, l_; fsplit(Ct[tl0 + i][dh], h_, l_);
                hbuf[i] = __builtin_bit_cast(unsigned short, h_);
                lbuf[i] = __builtin_bit_cast(unsigned short, l_);
            }
            uint4 uh0, uh1, ul0, ul1;
            uh0.x = hbuf[0]|(hbuf[1]<<16);  uh0.y = hbuf[2]|(hbuf[3]<<16);
            uh0.z = hbuf[4]|(hbuf[5]<<16);  uh0.w = hbuf[6]|(hbuf[7]<<16);
            uh1.x = hbuf[8]|(hbuf[9]<<16);  uh1.y = hbuf[10]|(hbuf[11]<<16);
            uh1.z = hbuf[12]|(hbuf[13]<<16);uh1.w = hbuf[14]|(hbuf[15]<<16);
            ul0.x = lbuf[0]|(lbuf[1]<<16);  ul0.y = lbuf[2]|(lbuf[3]<<16);
            ul0.z = lbuf[4]|(lbuf[5]<<16);  ul0.w = lbuf[6]|(lbuf[7]<<16);
            ul1.x = lbuf[8]|(lbuf[9]<<16);  ul1.y = lbuf[10]|(lbuf[11]<<16);
            ul1.z = lbuf[12]|(lbuf[13]<<16);ul1.w = lbuf[14]|(lbuf[15]<<16);
            *(uint4*)&vthi[rowb + tl0]     = uh0;
            *(uint4*)&vthi[rowb + tl0 + 8] = uh1;
            *(uint4*)&vtlo[rowb + tl0]     = ul0;
            *(uint4*)&vtlo[rowb + tl0 + 8] = ul1;
        }
    }
}

// ------------------------------------- flash attention, fp16x2 MFMA
// v7 = v3 structure + Q-prescale + packed cvt_pkrtz splits (P and O). Parked.
__global__ __launch_bounds__(256, 4) void attn_f16x2_kernel(
        const _Float16* __restrict__ qh, const _Float16* __restrict__ ql,
        const _Float16* __restrict__ kh, const _Float16* __restrict__ kl,
        const _Float16* __restrict__ vth, const _Float16* __restrict__ vtl,
        _Float16* __restrict__ oh, _Float16* __restrict__ ol) {
    __shared__ _Float16 Kh[64][72], Kl[64][72];   // doubles as Ph/Pl after QK^T
    __shared__ _Float16 Vh[64][72], Vl[64][72];
    int blk = blockIdx.x;
    blk = ((blk & 7) << 7) | (blk >> 3);   // grid=1024: 128 consecutive work-blocks per XCD
    int qt = blk & 15, bh = blk >> 4;
    int b = bh >> 3, hh = bh & 7;
    int q0 = qt << 6;
    int t = threadIdx.x;
    int w = t >> 6, lane = t & 63;
    int m16 = lane & 15, quad = lane >> 4;
    size_t bbase = (size_t)b * NVAR;
    size_t vbase = (size_t)bh * DH * NVAR;

    f16x8 qfh[2], qfl[2];
#pragma unroll
    for (int ks = 0; ks < 2; ++ks) {
        size_t gq = (bbase + q0 + w*16 + m16)*DM + hh*DH + ks*32 + quad*8;
        qfh[ks] = *(const f16x8*)&qh[gq] * (_Float16)0.125f;
        qfl[ks] = *(const f16x8*)&ql[gq] * (_Float16)0.125f;
    }

    float mrow[4] = {-1e30f,-1e30f,-1e30f,-1e30f};
    float lrow[4] = {0.f,0.f,0.f,0.f};
    f32x4 o1[4] = {}, o2[4] = {};

    for (int n0 = 0; n0 < NVAR; n0 += 64) {
        for (int idx = t; idx < 512; idx += 256) {
            int r = idx >> 3, cg = (idx & 7) << 3;
            size_t gk = (bbase + n0 + r)*DM + hh*DH + cg;
            size_t gv = vbase + (size_t)r*NVAR + n0 + cg;
            *(uint4*)&Kh[r][cg] = *(const uint4*)&kh[gk];
            *(uint4*)&Kl[r][cg] = *(const uint4*)&kl[gk];
            *(uint4*)&Vh[r][cg] = *(const uint4*)&vth[gv];
            *(uint4*)&Vl[r][cg] = *(const uint4*)&vtl[gv];
        }
        __syncthreads();

        f32x4 s1[4] = {}, s2[4] = {};
#pragma unroll
        for (int ks = 0; ks < 2; ++ks) {
#pragma unroll
            for (int nt = 0; nt < 4; ++nt) {
                f16x8 bh_ = *(const f16x8*)&Kh[nt*16 + m16][ks*32 + quad*8];
                f16x8 bl_ = *(const f16x8*)&Kl[nt*16 + m16][ks*32 + quad*8];
                s1[nt] = MFMA16(qfh[ks], bh_, s1[nt], 0, 0, 0);
                s2[nt] = MFMA16(qfh[ks], bl_, s2[nt], 0, 0, 0);
                s2[nt] = MFMA16(qfl[ks], bh_, s2[nt], 0, 0, 0);
            }
        }
        __syncthreads();   // all waves done reading K: Kh/Kl reusable as P

        float pbuf[4][4];
        float mx[4];
#pragma unroll
        for (int r = 0; r < 4; ++r) {
            float sv0 = fmaf(s2[0][r], ILSC, s1[0][r]);
            float sv1 = fmaf(s2[1][r], ILSC, s1[1][r]);
            float sv2 = fmaf(s2[2][r], ILSC, s1[2][r]);
            float sv3 = fmaf(s2[3][r], ILSC, s1[3][r]);
            pbuf[0][r] = sv0; pbuf[1][r] = sv1; pbuf[2][r] = sv2; pbuf[3][r] = sv3;
            mx[r] = rowmax16(fmaxf(fmaxf(sv0, sv1), fmaxf(sv2, sv3)));
        }
        bool grow = (mx[0] > mrow[0]) | (mx[1] > mrow[1]) |
                    (mx[2] > mrow[2]) | (mx[3] > mrow[3]);
        if (__any(grow)) {
#pragma unroll
            for (int r = 0; r < 4; ++r) {
                float mnew = fmaxf(mrow[r], mx[r]);
                float alpha = __expf(mrow[r] - mnew);
                mrow[r] = mnew;
                lrow[r] *= alpha;
#pragma unroll
                for (int nt = 0; nt < 4; ++nt) { o1[nt][r] *= alpha; o2[nt][r] *= alpha; }
            }
        }
#pragma unroll
        for (int r = 0; r < 4; ++r) {
            float p0 = __expf(pbuf[0][r] - mrow[r]);
            float p1 = __expf(pbuf[1][r] - mrow[r]);
            float p2 = __expf(pbuf[2][r] - mrow[r]);
            float p3 = __expf(pbuf[3][r] - mrow[r]);
            lrow[r] += rowsum16(p0 + p1 + p2 + p3);
            pbuf[0][r] = p0; pbuf[1][r] = p1; pbuf[2][r] = p2; pbuf[3][r] = p3;
        }
        // P -> LDS (into dead K tile), packed cvt. Intra-wave RAW via lgkmcnt.
#pragma unroll
        for (int nt = 0; nt < 4; ++nt)
#pragma unroll
            for (int rp = 0; rp < 2; ++rp) {
                f16x2 h2, l2;
                fsplit2(pbuf[nt][2*rp], pbuf[nt][2*rp + 1], h2, l2);
                Kh[w*16 + quad*4 + 2*rp][nt*16 + m16]     = h2.x;
                Kh[w*16 + quad*4 + 2*rp + 1][nt*16 + m16] = h2.y;
                Kl[w*16 + quad*4 + 2*rp][nt*16 + m16]     = l2.x;
                Kl[w*16 + quad*4 + 2*rp + 1][nt*16 + m16] = l2.y;
            }

#pragma unroll
        for (int ks = 0; ks < 2; ++ks) {
            f16x8 ph = *(const f16x8*)&Kh[w*16 + m16][ks*32 + quad*8];
            f16x8 pl = *(const f16x8*)&Kl[w*16 + m16][ks*32 + quad*8];
#pragma unroll
            for (int nt = 0; nt < 4; ++nt) {
                f16x8 vh_ = *(const f16x8*)&Vh[nt*16 + m16][ks*32 + quad*8];
                f16x8 vl_ = *(const f16x8*)&Vl[nt*16 + m16][ks*32 + quad*8];
                o1[nt] = MFMA16(ph, vh_, o1[nt], 0, 0, 0);
                o2[nt] = MFMA16(ph, vl_, o2[nt], 0, 0, 0);
                o2[nt] = MFMA16(pl, vh_, o2[nt], 0, 0, 0);
            }
        }
        __syncthreads();
    }
#pragma unroll
    for (int r = 0; r < 4; ++r) {
        float inv = 1.0f / lrow[r];
        size_t rowp = (bbase + q0 + w*16 + quad*4 + r)*DM + hh*DH;
        float ovv[4];
#pragma unroll
        for (int nt = 0; nt < 4; ++nt)
            ovv[nt] = fmaf(o2[nt][r], ILSC, o1[nt][r]) * inv;
#pragma unroll
        for (int np = 0; np < 2; ++np) {
            f16x2 h2, l2;
            fsplit2(ovv[2*np], ovv[2*np + 1], h2, l2);
            oh[rowp + (2*np)*16 + m16]     = h2.x;
            oh[rowp + (2*np + 1)*16 + m16] = h2.y;
            ol[rowp + (2*np)*16 + m16]     = l2.x;
            ol[rowp + (2*np + 1)*16 + m16] = l2.y;
        }
    }
}

// ---------------------------------------------------------------- LayerNorm
__global__ __launch_bounds__(256) void ln_kernel(
        _Float16* __restrict__ hhi, _Float16* __restrict__ hlo,
        const float* __restrict__ res,
        const float* __restrict__ w, const float* __restrict__ b) {
    int rowi = blockIdx.x, t = threadIdx.x;
    size_t base = (size_t)rowi * DM;
    int c = t << 1;
    f16x2 hv = *(const f16x2*)&hhi[base + c];
    f16x2 lv = *(const f16x2*)&hlo[base + c];
    float v0 = frec(hv.x, lv.x);
    float v1 = frec(hv.y, lv.y);
    if (res) { float2 rv = *(const float2*)&res[base + c]; v0 += rv.x; v1 += rv.y; }
    float s = v0 + v1, q = v0*v0 + v1*v1;
#pragma unroll
    for (int off = 1; off < 64; off <<= 1) {
        s += __shfl_xor(s, off);
        q += __shfl_xor(q, off);
    }
    __shared__ float sred[4], qred[4];
    int wid = t >> 6, lane = t & 63;
    if (lane == 0) { sred[wid] = s; qred[wid] = q; }
    __syncthreads();
    s = sred[0] + sred[1] + sred[2] + sred[3];
    q = qred[0] + qred[1] + qred[2] + qred[3];
    float m = s / (float)DM;
    float var = q / (float)DM - m*m;
    float inv = 1.0f / sqrtf(var + LN_EPS);
    float2 wv = *(const float2*)&w[c];
    float2 bv = *(const float2*)&b[c];
    float y0 = (v0 - m)*inv * wv.x + bv.x;
    float y1 = (v1 - m)*inv * wv.y + bv.y;
    f16x2 h2, l2; fsplit2(y0, y1, h2, l2);
    *(f16x2*)&hhi[base + c] = h2;
    *(f16x2*)&hlo[base + c] = l2;
}

__device__ __forceinline__ float gelu_exact(float xv) {
    return 0.5f * xv * (1.0f + erff(xv * 0.70710678118654752f));
}

// --------------------------------------- MoE FFN + fused LayerNorm (ln2)
__global__ __launch_bounds__(256) void moe_ln_kernel(
        _Float16* __restrict__ hhi, _Float16* __restrict__ hlo,
        const float* __restrict__ gW, const float* __restrict__ W1, const float* __restrict__ b1,
        const float* __restrict__ W2, const float* __restrict__ b2,
        const float* __restrict__ lw, const float* __restrict__ lb) {
    int tok = blockIdx.x, t = threadIdx.x;
    __shared__ float hs[DM];
    __shared__ float red[32][8];
    __shared__ float glog[8];
    __shared__ float hmid[8];
    __shared__ float wsel[2];
    __shared__ int   esel[2];
    __shared__ float sred[4], qred[4];
    size_t base = (size_t)tok * DM;
    int c = t << 1;
    f16x2 hv = *(const f16x2*)&hhi[base + c];
    f16x2 lv = *(const f16x2*)&hlo[base + c];
    float hv0 = frec(hv.x, lv.x);
    float hv1 = frec(hv.y, lv.y);
    hs[c] = hv0; hs[c + 1] = hv1;
    __syncthreads();
    int e = t & 7, i0 = t >> 3;
    {
        float a = 0.f;
        for (int i = i0; i < DM; i += 32) a += hs[i] * gW[i*NE + e];
        red[i0][e] = a;
    }
    __syncthreads();
    if (t < 8) { float sv = 0.f; for (int i = 0; i < 32; ++i) sv += red[i][t]; glog[t] = sv; }
    __syncthreads();
    if (t == 0) {
        float m0 = -1e30f, m1 = -1e30f; int s0i = 0, s1i = 0;
        for (int ei = 0; ei < 8; ++ei) {
            float vv = glog[ei];
            if (vv > m0) { m1 = m0; s1i = s0i; m0 = vv; s0i = ei; }
            else if (vv > m1) { m1 = vv; s1i = ei; }
        }
        float Z = 0.f;
        for (int ei = 0; ei < 8; ++ei) Z += expf(glog[ei] - m0);
        wsel[0] = 1.0f / Z;
        wsel[1] = expf(m1 - m0) / Z;
        esel[0] = s0i; esel[1] = s1i;
    }
    __syncthreads();
    float o0 = 0.f, o1 = 0.f;
    for (int ks = 0; ks < 2; ++ks) {
        int ee = esel[ks]; float wk = wsel[ks];
        int f = t & 7;
        float a = 0.f;
        for (int i = i0; i < DM; i += 32) a += hs[i] * W1[((size_t)ee*DM + i)*NF + f];
        red[i0][f] = a;
        __syncthreads();
        if (t < 8) {
            float sv = b1[ee*NF + t];
            for (int i = 0; i < 32; ++i) sv += red[i][t];
            hmid[t] = gelu_exact(sv);
        }
        __syncthreads();
        float2 b2v = *(const float2*)&b2[ee*DM + c];
        float s0v = b2v.x, s1v = b2v.y;
#pragma unroll
        for (int i = 0; i < NF; ++i) {
            float hm = hmid[i];
            float2 wpv = *(const float2*)&W2[((size_t)ee*NF + i)*DM + c];
            s0v += hm * wpv.x; s1v += hm * wpv.y;
        }
        o0 += wk * s0v; o1 += wk * s1v;
        __syncthreads();
    }
    // fused ln2: v = h + ffn
    float v0 = hv0 + o0, v1 = hv1 + o1;
    float s = v0 + v1, q = v0*v0 + v1*v1;
#pragma unroll
    for (int off = 1; off < 64; off <<= 1) {
        s += __shfl_xor(s, off);
        q += __shfl_xor(q, off);
    }
    int wid = t >> 6, lane = t & 63;
    if (lane == 0) { sred[wid] = s; qred[wid] = q; }
    __syncthreads();
    s = sred[0] + sred[1] + sred[2] + sred[3];
    q = qred[0] + qred[1] + qred[2] + qred[3];
    float m = s / (float)DM;
    float var = q / (float)DM - m*m;
    float inv = 1.0f / sqrtf(var + LN_EPS);
    float2 wv = *(const float2*)&lw[c];
    float2 bv = *(const float2*)&lb[c];
    float y0 = (v0 - m)*inv * wv.x + bv.x;
    float y1 = (v1 - m)*inv * wv.y + bv.y;
    f16x2 h2o, l2o; fsplit2(y0, y1, h2o, l2o);
    *(f16x2*)&hhi[base + c] = h2o;
    *(f16x2*)&hlo[base + c] = l2o;
}

// --------------------------- fused final LayerNorm + head gate (top-2 MoE)
__global__ __launch_bounds__(256) void encln_gate_kernel(
        _Float16* __restrict__ hhi, _Float16* __restrict__ hlo,
        const float* __restrict__ lw, const float* __restrict__ lb,
        const float* __restrict__ gW,
        int* __restrict__ sel, float2* __restrict__ wpair,
        int* __restrict__ cnt) {
    int tok = blockIdx.x, t = threadIdx.x;
    if (tok == 0 && t < NE) cnt[t] = 0;
    __shared__ float hs[DM];
    __shared__ float red[32][8];
    __shared__ float glog[8];
    __shared__ float sred[4], qred[4];
    size_t base = (size_t)tok * DM;
    int c = t << 1;
    f16x2 hv = *(const f16x2*)&hhi[base + c];
    f16x2 lv = *(const f16x2*)&hlo[base + c];
    float v0 = frec(hv.x, lv.x);
    float v1 = frec(hv.y, lv.y);
    float s = v0 + v1, q = v0*v0 + v1*v1;
#pragma unroll
    for (int off = 1; off < 64; off <<= 1) {
        s += __shfl_xor(s, off);
        q += __shfl_xor(q, off);
    }
    int wid = t >> 6, lane = t & 63;
    if (lane == 0) { sred[wid] = s; qred[wid] = q; }
    __syncthreads();
    s = sred[0] + sred[1] + sred[2] + sred[3];
    q = qred[0] + qred[1] + qred[2] + qred[3];
    float m = s / (float)DM;
    float var = q / (float)DM - m*m;
    float inv = 1.0f / sqrtf(var + LN_EPS);
    float2 wv = *(const float2*)&lw[c];
    float2 bv = *(const float2*)&lb[c];
    float y0 = (v0 - m)*inv * wv.x + bv.x;
    float y1 = (v1 - m)*inv * wv.y + bv.y;
    f16x2 h2o, l2o; fsplit2(y0, y1, h2o, l2o);
    *(f16x2*)&hhi[base + c] = h2o;
    *(f16x2*)&hlo[base + c] = l2o;
    hs[c] = y0; hs[c + 1] = y1;
    __syncthreads();
    int e = t & 7, i0 = t >> 3;
    float a = 0.f;
    for (int i = i0; i < DM; i += 32) a += hs[i] * gW[i*NE + e];
    red[i0][e] = a;
    __syncthreads();
    if (t < 8) { float sv = 0.f; for (int i = 0; i < 32; ++i) sv += red[i][t]; glog[t] = sv; }
    __syncthreads();
    if (t == 0) {
        float m0 = -1e30f, m1 = -1e30f; int s0i = 0, s1i = 0;
        for (int ei = 0; ei < 8; ++ei) {
            float vv = glog[ei];
            if (vv > m0) { m1 = m0; s1i = s0i; m0 = vv; s0i = ei; }
            else if (vv > m1) { m1 = vv; s1i = ei; }
        }
        float Z = 0.f;
        for (int ei = 0; ei < 8; ++ei) Z += __expf(glog[ei] - m0);
        float2 wvv;
        wvv.x = 1.0f / Z;
        wvv.y = __expf(m1 - m0) / Z;
        sel[tok] = s0i | (s1i << 3);
        wpair[tok] = wvv;
    }
}

// ------------------------------------------------------------- head: bucket
__global__ __launch_bounds__(64) void head_bucket_kernel(
        const int* __restrict__ sel, const float2* __restrict__ wpair,
        int* __restrict__ cnt, int* __restrict__ idxlist, float* __restrict__ wlist,
        int* __restrict__ pos0, int* __restrict__ pos1) {
    int lane = threadIdx.x;
    int tok = blockIdx.x*64 + lane;
    int s = sel[tok];
    int s0 = s & 7, s1 = (s >> 3) & 7;
    float2 wv = wpair[tok];
    unsigned long long lmask = (lane == 63) ? 0x7FFFFFFFFFFFFFFFull
                                            : ((1ull << lane) - 1ull);
#pragma unroll
    for (int e = 0; e < NE; ++e) {
        unsigned long long m0 = __ballot(s0 == e);
        unsigned long long m1 = __ballot(s1 == e);
        int tot = __popcll(m0) + __popcll(m1);
        int basep = 0;
        if (lane == 0 && tot > 0) basep = atomicAdd(&cnt[e], tot);
        basep = __shfl(basep, 0);
        if (s0 == e) {
            int p = basep + __popcll(m0 & lmask);
            idxlist[e*NTOK + p] = tok; wlist[e*NTOK + p] = wv.x;
            pos0[tok] = (e << 16) | p;
        }
        if (s1 == e) {
            int p = basep + __popcll(m0) + __popcll(m1 & lmask);
            idxlist[e*NTOK + p] = tok; wlist[e*NTOK + p] = wv.y;
            pos1[tok] = (e << 16) | p;
        }
    }
}

// ------------------------------------------------------------- head: prefix
__global__ __launch_bounds__(64) void head_prefix_kernel(int* __restrict__ cnt) {
    if (threadIdx.x == 0) {
        int run = 0, trun = 0;
        for (int e = 0; e < NE; ++e) {
            cnt[8 + e]  = run;  run  += cnt[e];
            cnt[16 + e] = trun; trun += (cnt[e] + 63) >> 6;
        }
        cnt[24] = trun;
    }
}

// --------------------------------------------- head: grouped GEMM, fp16x2 MFMA
// v3: [64x128] tile (4 n-quarters -> ~1052 live blocks, 4/CU), gload_lds
// staging (A-gather via per-lane global addr; lane's token row in a VGPR),
// linear 24KB LDS, split-f16 slot output (halves slot write+read traffic).
// Was: [64x256], reg-staged, fp32 slots -> 937 GB/s, 91.5us, occ 7.4%.
__global__ __launch_bounds__(256) void head_gemm_f16x2_kernel(
        const _Float16* __restrict__ hhi, const _Float16* __restrict__ hlo,
        const _Float16* __restrict__ hwhi, const _Float16* __restrict__ hwlo,
        const float* __restrict__ Hb,
        const int* __restrict__ cnt, const int* __restrict__ idxlist,
        const float* __restrict__ wlist,
        _Float16* __restrict__ slot_hi, _Float16* __restrict__ slot_lo) {
    int item = blockIdx.x;
    int total = cnt[24];
    if (item >= 4*total) return;
    int bn   = (item & 3) << 7;          // 0,128,256,384
    int tile = item >> 2;
    int e = 0;
#pragma unroll
    for (int ei = 1; ei < NE; ++ei) if (tile >= cnt[16 + ei]) e = ei;
    int m0 = (tile - cnt[16 + e]) << 6;
    int cnt_e = cnt[e];
    int rv = cnt_e - m0; if (rv > 64) rv = 64;
    int pref_e = cnt[8 + e];
    int t = threadIdx.x;
    int w = t >> 6, lane = t & 63, m16 = lane & 15, quad = lane >> 4;
    int wv = __builtin_amdgcn_readfirstlane(w);

    // LDS (f16 elems): AH[0,2048) AL[2048,4096) BH[4096,8192) BL[8192,12288)
    __shared__ _Float16 smem[12288];     // 24576 B
    __shared__ int   idxs[64];
    __shared__ float ws[64];
    if (t < 64) {
        int src = (t < rv) ? t : (rv - 1);
        idxs[t] = idxlist[e*NTOK + m0 + src];
        ws[t]   = (t < rv) ? wlist[e*NTOK + m0 + t] : 0.f;
    }
    __syncthreads();
    // lane's A-staging token row (loop-invariant)
    int arow_tok = idxs[wv*16 + (lane >> 2)];
    int lcol = (lane & 3) << 3;

    const _Float16* Wh = hwhi + (size_t)e*DM*DM;
    const _Float16* Wl = hwlo + (size_t)e*DM*DM;
    f32x4 a1[4][2] = {}, a2[4][2] = {};   // [mtile][ntile(2)]
    for (int k0 = 0; k0 < DM; k0 += 32) {
        // stage A rows (wave w -> rows w*16..+15, gathered)
        size_t ga = (size_t)arow_tok*DM + k0 + lcol;
        gload_lds16(&hhi[ga], &smem[(wv*16)*32]);
        gload_lds16(&hlo[ga], &smem[2048 + (wv*16)*32]);
        // stage B rows (wave w -> rows w*32..+31 per plane)
#pragma unroll
        for (int p = 0; p < 2; ++p) {
            size_t gb = (size_t)(bn + wv*32 + p*16 + (lane >> 2))*DM + k0 + lcol;
            gload_lds16(&Wh[gb], &smem[4096 + (wv*32 + p*16)*32]);
            gload_lds16(&Wl[gb], &smem[8192 + (wv*32 + p*16)*32]);
        }
        __syncthreads();
        f16x8 ah[4], al[4];
#pragma unroll
        for (int mt = 0; mt < 4; ++mt) {
            ah[mt] = *(const f16x8*)&smem[(mt*16 + m16)*32 + quad*8];
            al[mt] = *(const f16x8*)&smem[2048 + (mt*16 + m16)*32 + quad*8];
        }
#pragma unroll
        for (int nt = 0; nt < 2; ++nt) {
            f16x8 bh_ = *(const f16x8*)&smem[4096 + (w*32 + nt*16 + m16)*32 + quad*8];
            f16x8 bl_ = *(const f16x8*)&smem[8192 + (w*32 + nt*16 + m16)*32 + quad*8];
#pragma unroll
            for (int mt = 0; mt < 4; ++mt) {
                a1[mt][nt] = MFMA16(ah[mt], bh_, a1[mt][nt], 0, 0, 0);
                a2[mt][nt] = MFMA16(ah[mt], bl_, a2[mt][nt], 0, 0, 0);
                a2[mt][nt] = MFMA16(al[mt], bh_, a2[mt][nt], 0, 0, 0);
            }
        }
        __syncthreads();
    }
#pragma unroll
    for (int mt = 0; mt < 4; ++mt)
#pragma unroll
        for (int r = 0; r < 4; ++r) {
            int rloc = mt*16 + quad*4 + r;
            if (rloc < rv) {
                float wk = ws[rloc];
                size_t srow = (size_t)(pref_e + m0 + rloc)*DM;
#pragma unroll
                for (int nt = 0; nt < 2; ++nt) {
                    int gcol = bn + w*32 + nt*16 + m16;
                    float v = wk * (a1[mt][nt][r] + a2[mt][nt][r]*ILSC + Hb[e*DM + gcol]);
                    _Float16 h_, l_; fsplit(v, h_, l_);
                    slot_hi[srow + gcol] = h_;
                    slot_lo[srow + gcol] = l_;
                }
            }
        }
}

// ------------------------------------------------------------- head: combine+denorm
__global__ __launch_bounds__(256) void head_combine_kernel(
        const _Float16* __restrict__ slot_hi, const _Float16* __restrict__ slot_lo,
        const int* __restrict__ pos0, const int* __restrict__ pos1,
        const int* __restrict__ cnt,
        const float* __restrict__ rw, const float* __restrict__ rb,
        const float* __restrict__ mean, const float* __restrict__ stdd,
        float* __restrict__ out) {
    int tok = blockIdx.x, t = threadIdx.x;
    int n = tok & (NVAR - 1);
    int e0enc = pos0[tok], e1enc = pos1[tok];
    size_t s0 = (size_t)(cnt[8 + (e0enc >> 16)] + (e0enc & 0xFFFF)) * DM;
    size_t s1 = (size_t)(cnt[8 + (e1enc >> 16)] + (e1enc & 0xFFFF)) * DM;
    size_t base = (size_t)tok * DM;
    float mn = mean[tok], sd = stdd[tok];
    float rwv = rw[n] + 1e-10f, rbv = rb[n];
    float o0 = frec(slot_hi[s0 + t], slot_lo[s0 + t])
             + frec(slot_hi[s1 + t], slot_lo[s1 + t]);
    float o1 = frec(slot_hi[s0 + t + 256], slot_lo[s0 + t + 256])
             + frec(slot_hi[s1 + t + 256], slot_lo[s1 + t + 256]);
    out[base + t]       = (o0 - rbv) / rwv * sd + mn;
    out[base + t + 256] = (o1 - rbv) / rwv * sd + mn;
}

// ---------------------------------------------------------------- launch
extern "C" void kernel_launch(void* const* d_in, const int* in_sizes, int n_in,
                              void* d_out, int out_size, void* d_ws, size_t ws_size,
                              hipStream_t stream) {
    const float* x       = (const float*)d_in[0];
    const float* revin_w = (const float*)d_in[1];
    const float* revin_b = (const float*)d_in[2];
    const float* emb_W   = (const float*)d_in[3];
    const float* emb_b   = (const float*)d_in[4];
    const float* Wq      = (const float*)d_in[5];
    const float* bq      = (const float*)d_in[6];
    const float* Wk      = (const float*)d_in[7];
    const float* bk      = (const float*)d_in[8];
    const float* Wv      = (const float*)d_in[9];
    const float* bv      = (const float*)d_in[10];
    const float* Wo      = (const float*)d_in[11];
    const float* bo      = (const float*)d_in[12];
    const float* ln1_w   = (const float*)d_in[13];
    const float* ln1_b   = (const float*)d_in[14];
    const float* ln2_w   = (const float*)d_in[15];
    const float* ln2_b   = (const float*)d_in[16];
    const float* gate_W  = (const float*)d_in[17];
    const float* eW1     = (const float*)d_in[18];
    const float* eb1     = (const float*)d_in[19];
    const float* eW2     = (const float*)d_in[20];
    const float* eb2     = (const float*)d_in[21];
    const float* enc_w   = (const float*)d_in[22];
    const float* enc_b   = (const float*)d_in[23];
    const float* hgW     = (const float*)d_in[24];
    const float* hW      = (const float*)d_in[25];
    const float* hb      = (const float*)d_in[26];
    float* out = (float*)d_out;

    const size_t TOKD = (size_t)NTOK * DM;   // 4194304
    float* ws   = (float*)d_ws;
    float* mean = ws;
    float* stdd = ws + 8192;
    _Float16* hhi  = (_Float16*)(ws + 16384);
    _Float16* hlo  = hhi + TOKD;
    _Float16* qhi  = hlo + TOKD;     // head stage: slot_hi spans qhi..qlo (16 MB)
    _Float16* qlo  = qhi + TOKD;
    _Float16* khi  = qlo + TOKD;     // head stage: slot_lo spans khi..klo; also proj fp32
    _Float16* klo  = khi + TOKD;
    _Float16* vthi = klo + TOKD;     // head stage: head split weights
    _Float16* vtlo = vthi + TOKD;
    _Float16* whi  = vtlo + TOKD;    // 9 transposed split weights
    _Float16* wlo  = whi + (size_t)9*DM*DM;
    int*   cnt     = (int*)(wlo + (size_t)9*DM*DM);   // [0..7]=cnt,[8..15]=tok prefix,[16..23]=tile prefix,[24]=total
    int*   idxlist = cnt + 32;
    float* wlist   = (float*)(idxlist + NE*NTOK);
    int*   sel     = (int*)(wlist + NE*NTOK);
    float2* wpair  = (float2*)(sel + NTOK);
    int*   pos0    = (int*)(wpair + NTOK);
    int*   pos1    = pos0 + NTOK;
    float* proj    = (float*)khi;
    _Float16* slot_hi = qhi;         // 2*NTOK rows x DM f16
    _Float16* slot_lo = khi;

    dim3 blk(256);
    dim3 ggemm(DM/64, NTOK/128);     // (8, 64)

    revin_stats_kernel<<<dim3(BATCH*16), blk, 0, stream>>>(x, mean, stdd);
    revin_norm_kernel<<<dim3(NVAR/32, SEQ/32, BATCH), blk, 0, stream>>>(
        x, mean, stdd, revin_w, revin_b, qhi, qlo);

    WSrcs srcs;
    srcs.p[0] = emb_W;
    for (int l = 0; l < NL; ++l) {
        srcs.p[1 + l*4 + 0] = Wq + (size_t)l*DM*DM;
        srcs.p[1 + l*4 + 1] = Wk + (size_t)l*DM*DM;
        srcs.p[1 + l*4 + 2] = Wv + (size_t)l*DM*DM;
        srcs.p[1 + l*4 + 3] = Wo + (size_t)l*DM*DM;
    }
    transpose_w_kernel<<<dim3(8, 8, 9), blk, 0, stream>>>(srcs, whi, wlo);

    gemm_f16x2_kernel<<<ggemm, blk, 0, stream>>>(
        qhi, qlo, whi, wlo, emb_b, nullptr, hhi, hlo, NTOK, SEQ, DM);

    for (int l = 0; l < NL; ++l) {
        size_t oq = (size_t)(1 + l*4 + 0)*DM*DM;   // Wq^T; Wk^T contiguous after
        size_t ov = (size_t)(1 + l*4 + 2)*DM*DM;
        size_t oo = (size_t)(1 + l*4 + 3)*DM*DM;
        gemm_qkvt_kernel<<<dim3(1536), blk, 0, stream>>>(
            hhi, hlo, whi + oq, wlo + oq, whi + ov, wlo + ov,
            bq + l*DM, bk + l*DM, bv + l*DM,
            qhi, qlo, khi, klo, vthi, vtlo);
        attn_f16x2_kernel<<<dim3(64*16), blk, 0, stream>>>(
            qhi, qlo, khi, klo, vthi, vtlo, qhi, qlo);
        gemm_f16x2_kernel<<<ggemm, blk, 0, stream>>>(
            qhi, qlo, whi + oo, wlo + oo, bo + l*DM, proj, nullptr, nullptr, NTOK, DM, DM);
        ln_kernel<<<dim3(NTOK), blk, 0, stream>>>(hhi, hlo, proj, ln1_w + l*DM, ln1_b + l*DM);
        moe_ln_kernel<<<dim3(NTOK), blk, 0, stream>>>(
            hhi, hlo, gate_W + (size_t)l*DM*NE,
            eW1 + (size_t)l*NE*DM*NF, eb1 + (size_t)l*NE*NF,
            eW2 + (size_t)l*NE*NF*DM, eb2 + (size_t)l*NE*DM,
            ln2_w + l*DM, ln2_b + l*DM);
    }

    // head expert weights -> split f16 in the (now dead) vt planes
    WSrcs hsrcs;
    for (int e = 0; e < NE; ++e) hsrcs.p[e] = hW + (size_t)e*DM*DM;
    hsrcs.p[8] = hW;   // unused
    transpose_w_kernel<<<dim3(8, 8, 8), blk, 0, stream>>>(hsrcs, vthi, vtlo);

    encln_gate_kernel<<<dim3(NTOK), blk, 0, stream>>>(
        hhi, hlo, enc_w, enc_b, hgW, sel, wpair, cnt);
    head_bucket_kernel<<<dim3(NTOK/64), dim3(64), 0, stream>>>(
        sel, wpair, cnt, idxlist, wlist, pos0, pos1);
    head_prefix_kernel<<<dim3(1), dim3(64), 0, stream>>>(cnt);
    // max tiles: 263 -> 4*263=1052 work items; pad to 1088
    head_gemm_f16x2_kernel<<<dim3(1088), blk, 0, stream>>>(
        hhi, hlo, vthi, vtlo, hb, cnt, idxlist, wlist, slot_hi, slot_lo);
    head_combine_kernel<<<dim3(NTOK), blk, 0, stream>>>(
        slot_hi, slot_lo, pos0, pos1, cnt, revin_w, revin_b, mean, stdd, out);
}